// Round 1
// baseline (7743.517 us; speedup 1.0000x reference)
//
#include <hip/hip_runtime.h>
#include <math.h>

#define E_DIM 768
#define NTOK 1025
#define B_DIM 32
#define NHEADS 12
#define HDIM 64
#define LAYERS 12
#define FF_DIM 3072
#define P2 576

// ---------------- helpers ----------------
__device__ __forceinline__ float block_reduce_sum(float v, float* red) {
  int tid = threadIdx.x;
  red[tid] = v;
  __syncthreads();
#pragma unroll
  for (int s = 128; s > 0; s >>= 1) {
    if (tid < s) red[tid] += red[tid + s];
    __syncthreads();
  }
  float r = red[0];
  __syncthreads();
  return r;
}

// ---------------- embed GEMM: scene = masks @ emb_W^T + b + pos ----------------
// A [32768,576], W [768,576]; writes scene[b,1+nt,e]
__global__ __launch_bounds__(256) void embed_gemm(
    const float* __restrict__ A, const float* __restrict__ W,
    const float* __restrict__ bias, const float* __restrict__ pos,
    float* __restrict__ scene) {
  __shared__ float Xs[16][64];
  __shared__ float Ws[16][64];
  int tid = threadIdx.x;
  int n0 = blockIdx.x * 64;
  int m0 = blockIdx.y * 64;
  int lr = tid >> 2;
  int lk = (tid & 3) << 2;
  int ty = tid >> 4, tx = tid & 15;
  float acc[4][4] = {};
  for (int k0 = 0; k0 < P2; k0 += 16) {
    float4 xv = *(const float4*)(A + (size_t)(m0 + lr) * P2 + k0 + lk);
    float4 wv = *(const float4*)(W + (size_t)(n0 + lr) * P2 + k0 + lk);
    Xs[lk + 0][lr] = xv.x; Xs[lk + 1][lr] = xv.y; Xs[lk + 2][lr] = xv.z; Xs[lk + 3][lr] = xv.w;
    Ws[lk + 0][lr] = wv.x; Ws[lk + 1][lr] = wv.y; Ws[lk + 2][lr] = wv.z; Ws[lk + 3][lr] = wv.w;
    __syncthreads();
#pragma unroll
    for (int kk = 0; kk < 16; ++kk) {
      float4 a4 = *(const float4*)&Xs[kk][ty << 2];
      float4 b4 = *(const float4*)&Ws[kk][tx << 2];
      float av[4] = {a4.x, a4.y, a4.z, a4.w};
      float bv[4] = {b4.x, b4.y, b4.z, b4.w};
#pragma unroll
      for (int i = 0; i < 4; ++i)
#pragma unroll
        for (int j = 0; j < 4; ++j) acc[i][j] += av[i] * bv[j];
    }
    __syncthreads();
  }
#pragma unroll
  for (int i = 0; i < 4; ++i) {
    int m = m0 + (ty << 2) + i;
    int b = m >> 10, nt = m & 1023;
    size_t row = (size_t)b * NTOK + 1 + nt;
#pragma unroll
    for (int j = 0; j < 4; ++j) {
      int n = n0 + (tx << 2) + j;
      scene[row * E_DIM + n] = acc[i][j] + bias[n] + pos[(size_t)(1 + nt) * E_DIM + n];
    }
  }
}

// scene token 0 = class_embed + scene_pos[0]
__global__ void scene_cls(const float* __restrict__ cls, const float* __restrict__ pos,
                          float* __restrict__ scene) {
  int b = blockIdx.x;
  for (int e = threadIdx.x; e < E_DIM; e += 256)
    scene[(size_t)b * NTOK * E_DIM + e] = cls[e] + pos[e];
}

// in-place row normalize (no gamma/beta): one block per row of 768
__global__ __launch_bounds__(256) void ln_rows(const float* __restrict__ in, float* __restrict__ out) {
  __shared__ float red[256];
  int r = blockIdx.x, tid = threadIdx.x;
  const float* x = in + (size_t)r * E_DIM;
  float a0 = x[tid], a1 = x[tid + 256], a2 = x[tid + 512];
  float mean = block_reduce_sum(a0 + a1 + a2, red) * (1.f / 768.f);
  float d0 = a0 - mean, d1 = a1 - mean, d2 = a2 - mean;
  float var = block_reduce_sum(d0 * d0 + d1 * d1 + d2 * d2, red) * (1.f / 768.f);
  float rinv = rsqrtf(var + 1e-5f);
  float* o = out + (size_t)r * E_DIM;
  o[tid] = d0 * rinv; o[tid + 256] = d1 * rinv; o[tid + 512] = d2 * rinv;
}

// tgt rows: [b,0]=cls+tp[0]; [b,1]=mask@W^T+b+tp[1]
__global__ __launch_bounds__(256) void tgt_init(
    const float* __restrict__ tmask, const float* __restrict__ W,
    const float* __restrict__ bias, const float* __restrict__ cls,
    const float* __restrict__ tpos, float* __restrict__ tq) {
  int b = blockIdx.x, tid = threadIdx.x;
  for (int e = tid; e < E_DIM; e += 256)
    tq[(size_t)(b * 2) * E_DIM + e] = cls[e] + tpos[e];
  const float* tm = tmask + (size_t)b * P2;
  for (int e = tid; e < E_DIM; e += 256) {
    const float* wr = W + (size_t)e * P2;
    float s = 0.f;
    for (int k = 0; k < P2; k += 4) {
      float4 w4 = *(const float4*)&wr[k];
      float4 t4 = *(const float4*)&tm[k];
      s += w4.x * t4.x + w4.y * t4.y + w4.z * t4.z + w4.w * t4.w;
    }
    tq[(size_t)(b * 2 + 1) * E_DIM + e] = s + bias[e] + tpos[E_DIM + e];
  }
}

// M[l][d,dp] = sum_e Wq[l][e,d] * Wk[l][e,dp]
__global__ void prep_m(const float* __restrict__ Wq, const float* __restrict__ Wk,
                       float* __restrict__ Mb) {
  int l = blockIdx.y;
  int idx = blockIdx.x * 256 + threadIdx.x;  // 0..4095
  int d = idx >> 6, dp = idx & 63;
  const float* wq = Wq + l * 4096;
  const float* wk = Wk + l * 4096;
  float s = 0.f;
#pragma unroll 8
  for (int e = 0; e < 64; ++e) s += wq[e * 64 + d] * wk[e * 64 + dp];
  Mb[l * 4096 + idx] = s;
}

// Wvo[e', h*64+d] = sum_ev Wv[l][ev,d] * Wo[l][e', h*64+ev]
__global__ void prep_wvo(const float* __restrict__ Wv, const float* __restrict__ Wo,
                         float* __restrict__ Wvo, int l) {
  int idx = blockIdx.x * 256 + threadIdx.x;  // over 768*768
  int ep = idx / 768, hd = idx % 768;
  int h = hd >> 6, d = hd & 63;
  const float* wv = Wv + (size_t)l * 4096;
  const float* wo = Wo + (size_t)l * 768 * 768 + (size_t)ep * 768 + h * 64;
  float s = 0.f;
#pragma unroll 8
  for (int ev = 0; ev < 64; ++ev) s += wv[ev * 64 + d] * wo[ev];
  Wvo[idx] = s;
}

// per target row: LN(tq)*g+b, then qM = q @ M_l; emit qMg (g-folded, scaled) and qMb
__global__ __launch_bounds__(256) void qln_qm(
    const float* __restrict__ tq, const float* __restrict__ g1,
    const float* __restrict__ b1, const float* __restrict__ Mb, int l,
    float* __restrict__ qMg, float* __restrict__ qMb) {
  __shared__ float q[768];
  __shared__ float qm[768];
  __shared__ float red[256];
  int r = blockIdx.x, tid = threadIdx.x;
  const float* x = tq + (size_t)r * E_DIM;
  float a0 = x[tid], a1 = x[tid + 256], a2 = x[tid + 512];
  float mean = block_reduce_sum(a0 + a1 + a2, red) * (1.f / 768.f);
  float d0 = a0 - mean, d1 = a1 - mean, d2 = a2 - mean;
  float var = block_reduce_sum(d0 * d0 + d1 * d1 + d2 * d2, red) * (1.f / 768.f);
  float rinv = rsqrtf(var + 1e-5f);
  const float* gl = g1 + l * E_DIM;
  const float* bl = b1 + l * E_DIM;
  q[tid] = d0 * rinv * gl[tid] + bl[tid];
  q[tid + 256] = d1 * rinv * gl[tid + 256] + bl[tid + 256];
  q[tid + 512] = d2 * rinv * gl[tid + 512] + bl[tid + 512];
  __syncthreads();
  const float* M = Mb + l * 4096;
  const float inv_scale = rsqrtf(768.f);
  for (int o = tid; o < 768; o += 256) {
    int h = o >> 6, dp = o & 63;
    const float* qh = q + h * 64;
    float s = 0.f;
#pragma unroll 8
    for (int d = 0; d < 64; ++d) s += qh[d] * M[d * 64 + dp];
    qm[o] = s;
    qMg[(size_t)r * E_DIM + o] = s * gl[o] * inv_scale;
  }
  __syncthreads();
  if (tid < NHEADS) {
    float acc = 0.f;
#pragma unroll 8
    for (int dp = 0; dp < 64; ++dp) acc += qm[tid * 64 + dp] * bl[tid * 64 + dp];
    qMb[r * NHEADS + tid] = acc * inv_scale;
  }
}

// fused energy + softmax + ctx over k=0..1024; one block per (b,h), both t
__global__ __launch_bounds__(256) void attn_kernel(
    const float* __restrict__ ns, const float* __restrict__ qMg,
    const float* __restrict__ qMb, const float* __restrict__ g1,
    const float* __restrict__ b1, int l, float* __restrict__ ctx) {
  __shared__ float e0[NTOK], e1[NTOK];
  __shared__ float qg0[64], qg1[64];
  __shared__ float red[256];
  __shared__ float cp[8][64];
  int b = blockIdx.x / NHEADS;
  int h = blockIdx.x % NHEADS;
  int tid = threadIdx.x;
  int r0 = b * 2, r1 = r0 + 1;
  if (tid < 64) {
    qg0[tid] = qMg[(size_t)r0 * E_DIM + h * 64 + tid];
    qg1[tid] = qMg[(size_t)r1 * E_DIM + h * 64 + tid];
  }
  __syncthreads();
  float qb0 = qMb[r0 * NHEADS + h], qb1 = qMb[r1 * NHEADS + h];
  const float* nsb = ns + (size_t)b * NTOK * E_DIM + h * 64;
  float mx0 = -1e30f, mx1 = -1e30f;
  for (int k = tid; k < NTOK; k += 256) {
    const float* row = nsb + (size_t)k * E_DIM;
    float d0 = 0.f, d1 = 0.f;
#pragma unroll
    for (int j = 0; j < 64; j += 4) {
      float4 v = *(const float4*)(row + j);
      d0 += v.x * qg0[j] + v.y * qg0[j + 1] + v.z * qg0[j + 2] + v.w * qg0[j + 3];
      d1 += v.x * qg1[j] + v.y * qg1[j + 1] + v.z * qg1[j + 2] + v.w * qg1[j + 3];
    }
    d0 += qb0; d1 += qb1;
    e0[k] = d0; e1[k] = d1;
    mx0 = fmaxf(mx0, d0); mx1 = fmaxf(mx1, d1);
  }
  red[tid] = mx0; __syncthreads();
  for (int s = 128; s > 0; s >>= 1) { if (tid < s) red[tid] = fmaxf(red[tid], red[tid + s]); __syncthreads(); }
  float M0 = red[0]; __syncthreads();
  red[tid] = mx1; __syncthreads();
  for (int s = 128; s > 0; s >>= 1) { if (tid < s) red[tid] = fmaxf(red[tid], red[tid + s]); __syncthreads(); }
  float M1 = red[0]; __syncthreads();
  float s0 = 0.f, s1 = 0.f;
  for (int k = tid; k < NTOK; k += 256) {
    float p0 = expf(e0[k] - M0); e0[k] = p0; s0 += p0;
    float p1 = expf(e1[k] - M1); e1[k] = p1; s1 += p1;
  }
  float S0 = block_reduce_sum(s0, red);
  float S1 = block_reduce_sum(s1, red);
  float inv0 = 1.f / S0, inv1 = 1.f / S1;
  int d = tid & 63, grp = tid >> 6;
  float a0 = 0.f, a1 = 0.f;
  for (int k = grp; k < NTOK; k += 4) {
    float v = nsb[(size_t)k * E_DIM + d];
    a0 += e0[k] * v;
    a1 += e1[k] * v;
  }
  cp[grp][d] = a0;
  cp[4 + grp][d] = a1;
  __syncthreads();
  if (tid < 128) {
    int t = tid >> 6, dd = tid & 63;
    int o = h * 64 + dd;
    float gg = g1[l * E_DIM + o], bb = b1[l * E_DIM + o];
    if (t == 0) {
      float s = (cp[0][dd] + cp[1][dd] + cp[2][dd] + cp[3][dd]) * inv0;
      ctx[(size_t)r0 * E_DIM + o] = s * gg + bb;
    } else {
      float s = (cp[4][dd] + cp[5][dd] + cp[6][dd] + cp[7][dd]) * inv1;
      ctx[(size_t)r1 * E_DIM + o] = s * gg + bb;
    }
  }
}

// one block per row m: out[m,n] = X[m,:]·W[n,:] + bias[n]; optional relu;
// optional fused residual + layernorm (requires N==768, gridDim.y==1)
__global__ __launch_bounds__(256) void row_gemm(
    const float* __restrict__ X, int K, const float* __restrict__ W,
    const float* __restrict__ bias, int N, int relu,
    const float* __restrict__ res, const float* __restrict__ g,
    const float* __restrict__ bsh, float* __restrict__ out) {
  __shared__ float xs[3072];
  __shared__ float ys[768];
  __shared__ float red[256];
  int m = blockIdx.x, tid = threadIdx.x;
  const float* xrow = X + (size_t)m * K;
  for (int k = tid * 4; k < K; k += 1024)
    *(float4*)&xs[k] = *(const float4*)&xrow[k];
  __syncthreads();
  int nseg = N / gridDim.y;
  int n0 = blockIdx.y * nseg;
  for (int n = n0 + tid; n < n0 + nseg; n += 256) {
    const float* wrow = W + (size_t)n * K;
    float s = 0.f;
#pragma unroll 4
    for (int k = 0; k < K; k += 4) {
      float4 wv = *(const float4*)&wrow[k];
      float4 xv = *(const float4*)&xs[k];
      s += wv.x * xv.x + wv.y * xv.y + wv.z * xv.z + wv.w * xv.w;
    }
    s += bias[n];
    if (relu) s = fmaxf(s, 0.f);
    if (g) ys[n - n0] = s;
    else out[(size_t)m * N + n] = s;
  }
  if (g) {
    __syncthreads();
    float t0 = ys[tid] + res[(size_t)m * 768 + tid];
    float t1 = ys[tid + 256] + res[(size_t)m * 768 + tid + 256];
    float t2 = ys[tid + 512] + res[(size_t)m * 768 + tid + 512];
    float mean = block_reduce_sum(t0 + t1 + t2, red) * (1.f / 768.f);
    float d0 = t0 - mean, d1 = t1 - mean, d2 = t2 - mean;
    float var = block_reduce_sum(d0 * d0 + d1 * d1 + d2 * d2, red) * (1.f / 768.f);
    float rinv = rsqrtf(var + 1e-5f);
    out[(size_t)m * 768 + tid] = d0 * rinv * g[tid] + bsh[tid];
    out[(size_t)m * 768 + tid + 256] = d1 * rinv * g[tid + 256] + bsh[tid + 256];
    out[(size_t)m * 768 + tid + 512] = d2 * rinv * g[tid + 512] + bsh[tid + 512];
  }
}

// mean over the 2 target tokens
__global__ void mean_rows(const float* __restrict__ tq, float* __restrict__ xm) {
  int idx = blockIdx.x * 256 + threadIdx.x;  // 32*768
  int b = idx / E_DIM, e = idx % E_DIM;
  xm[idx] = 0.5f * (tq[(size_t)(b * 2) * E_DIM + e] + tq[(size_t)(b * 2 + 1) * E_DIM + e]);
}

// top-5 (desc, ties -> lower index) -> one-hot [5,1025] per batch
__global__ __launch_bounds__(256) void top5_onehot(const float* __restrict__ logits,
                                                   float* __restrict__ out) {
  __shared__ float v[1024];
  __shared__ float bv[256];
  __shared__ int bi[256];
  int b = blockIdx.x, tid = threadIdx.x;
  for (int i = tid; i < 1024; i += 256) v[i] = logits[(size_t)b * 1024 + i];
  float* ob = out + (size_t)b * 5 * NTOK;
  for (int i = tid; i < 5 * NTOK; i += 256) ob[i] = 0.f;
  __syncthreads();
  for (int it = 0; it < 5; ++it) {
    float best = -1e38f;
    int bidx = 0x7fffffff;
    for (int i = tid; i < 1024; i += 256) {
      float x = v[i];
      if (x > best || (x == best && i < bidx)) { best = x; bidx = i; }
    }
    bv[tid] = best; bi[tid] = bidx;
    __syncthreads();
    for (int s = 128; s > 0; s >>= 1) {
      if (tid < s) {
        if (bv[tid + s] > bv[tid] || (bv[tid + s] == bv[tid] && bi[tid + s] < bi[tid])) {
          bv[tid] = bv[tid + s]; bi[tid] = bi[tid + s];
        }
      }
      __syncthreads();
    }
    if (tid == 0) {
      ob[it * NTOK + bi[0]] = 1.0f;
      v[bi[0]] = -1e38f;
    }
    __syncthreads();
  }
}

extern "C" void kernel_launch(void* const* d_in, const int* in_sizes, int n_in,
                              void* d_out, int out_size, void* d_ws, size_t ws_size,
                              hipStream_t stream) {
  const float* scene_masks = (const float*)d_in[0];
  const float* target_mask = (const float*)d_in[1];
  const float* emb_W = (const float*)d_in[2];
  const float* emb_b = (const float*)d_in[3];
  const float* class_embed = (const float*)d_in[4];
  const float* scene_pos = (const float*)d_in[5];
  const float* target_pos = (const float*)d_in[6];
  const float* ln1_g = (const float*)d_in[7];
  const float* ln1_b = (const float*)d_in[8];
  const float* ln2_g = (const float*)d_in[9];
  const float* ln2_b = (const float*)d_in[10];
  const float* Wq = (const float*)d_in[11];
  const float* Wk = (const float*)d_in[12];
  const float* Wv = (const float*)d_in[13];
  const float* Wo = (const float*)d_in[14];
  const float* bo = (const float*)d_in[15];
  const float* W1 = (const float*)d_in[16];
  const float* fb1 = (const float*)d_in[17];
  const float* W2 = (const float*)d_in[18];
  const float* fb2 = (const float*)d_in[19];
  const float* mlp_W = (const float*)d_in[20];
  const float* mlp_b = (const float*)d_in[21];
  float* out = (float*)d_out;

  float* ws = (float*)d_ws;
  float* scene = ws;                       // 32*1025*768 = 25190400
  float* Mbuf = scene + 25190400;          // 12*4096 = 49152
  float* Wvo = Mbuf + 49152;               // 589824
  float* tq = Wvo + 589824;                // 49152
  float* qMg = tq + 49152;                 // 49152
  float* qMb = qMg + 49152;                // 768
  float* ctxf = qMb + 768;                 // 49152
  float* xbuf = ctxf + 49152;              // 49152
  float* h1 = xbuf + 49152;                // 196608
  float* xm = h1 + 196608;                 // 24576
  float* logits = xm + 24576;              // 32768

  // ---- setup ----
  embed_gemm<<<dim3(12, 512), 256, 0, stream>>>(scene_masks, emb_W, emb_b, scene_pos, scene);
  scene_cls<<<32, 256, 0, stream>>>(class_embed, scene_pos, scene);
  ln_rows<<<32 * NTOK, 256, 0, stream>>>(scene, scene);  // in-place normalize
  tgt_init<<<32, 256, 0, stream>>>(target_mask, emb_W, emb_b, class_embed, target_pos, tq);
  prep_m<<<dim3(16, 12), 256, 0, stream>>>(Wq, Wk, Mbuf);

  // ---- 12 transformer blocks on the 2-token target path ----
  for (int l = 0; l < LAYERS; ++l) {
    qln_qm<<<64, 256, 0, stream>>>(tq, ln1_g, ln1_b, Mbuf, l, qMg, qMb);
    attn_kernel<<<32 * NHEADS, 256, 0, stream>>>(scene, qMg, qMb, ln1_g, ln1_b, l, ctxf);
    prep_wvo<<<2304, 256, 0, stream>>>(Wv, Wo, Wvo, l);
    // out2 = ctx @ Wvo^T + bo; x = LN(out2 + tq)*g1+b1
    row_gemm<<<dim3(64, 1), 256, 0, stream>>>(ctxf, 768, Wvo, bo + l * 768, 768, 0,
                                              tq, ln1_g + l * 768, ln1_b + l * 768, xbuf);
    // h1 = relu(x @ W1^T + b1)
    row_gemm<<<dim3(64, 4), 256, 0, stream>>>(xbuf, 768, W1 + (size_t)l * FF_DIM * 768,
                                              fb1 + l * FF_DIM, FF_DIM, 1,
                                              nullptr, nullptr, nullptr, h1);
    // f2 = h1 @ W2^T + b2; tq = LN(f2 + x)*g2+b2
    row_gemm<<<dim3(64, 1), 256, 0, stream>>>(h1, FF_DIM, W2 + (size_t)l * 768 * FF_DIM,
                                              fb2 + l * 768, 768, 0,
                                              xbuf, ln2_g + l * 768, ln2_b + l * 768, tq);
  }

  // ---- head ----
  mean_rows<<<96, 256, 0, stream>>>(tq, xm);
  row_gemm<<<dim3(32, 1), 256, 0, stream>>>(xm, 768, mlp_W, mlp_b, 1024, 0,
                                            nullptr, nullptr, nullptr, logits);
  top5_onehot<<<32, 256, 0, stream>>>(logits, out);
}

// Round 2
// 2946.518 us; speedup vs baseline: 2.6280x; 2.6280x over previous
//
#include <hip/hip_runtime.h>
#include <math.h>

#define E_DIM 768
#define NTOK 1025
#define B_DIM 32
#define NHEADS 12
#define HDIM 64
#define LAYERS 12
#define FF_DIM 3072
#define P2 576

// ---------------- helpers ----------------
__device__ __forceinline__ float block_reduce_sum(float v, float* red) {
  int tid = threadIdx.x;
  red[tid] = v;
  __syncthreads();
#pragma unroll
  for (int s = 128; s > 0; s >>= 1) {
    if (tid < s) red[tid] += red[tid + s];
    __syncthreads();
  }
  float r = red[0];
  __syncthreads();
  return r;
}

// ---------------- embed GEMM: scene = masks @ emb_W^T + b + pos ----------------
__global__ __launch_bounds__(256) void embed_gemm(
    const float* __restrict__ A, const float* __restrict__ W,
    const float* __restrict__ bias, const float* __restrict__ pos,
    float* __restrict__ scene) {
  __shared__ float Xs[16][64];
  __shared__ float Ws[16][64];
  int tid = threadIdx.x;
  int n0 = blockIdx.x * 64;
  int m0 = blockIdx.y * 64;
  int lr = tid >> 2;
  int lk = (tid & 3) << 2;
  int ty = tid >> 4, tx = tid & 15;
  float acc[4][4] = {};
  for (int k0 = 0; k0 < P2; k0 += 16) {
    float4 xv = *(const float4*)(A + (size_t)(m0 + lr) * P2 + k0 + lk);
    float4 wv = *(const float4*)(W + (size_t)(n0 + lr) * P2 + k0 + lk);
    Xs[lk + 0][lr] = xv.x; Xs[lk + 1][lr] = xv.y; Xs[lk + 2][lr] = xv.z; Xs[lk + 3][lr] = xv.w;
    Ws[lk + 0][lr] = wv.x; Ws[lk + 1][lr] = wv.y; Ws[lk + 2][lr] = wv.z; Ws[lk + 3][lr] = wv.w;
    __syncthreads();
#pragma unroll
    for (int kk = 0; kk < 16; ++kk) {
      float4 a4 = *(const float4*)&Xs[kk][ty << 2];
      float4 b4 = *(const float4*)&Ws[kk][tx << 2];
      float av[4] = {a4.x, a4.y, a4.z, a4.w};
      float bv[4] = {b4.x, b4.y, b4.z, b4.w};
#pragma unroll
      for (int i = 0; i < 4; ++i)
#pragma unroll
        for (int j = 0; j < 4; ++j) acc[i][j] += av[i] * bv[j];
    }
    __syncthreads();
  }
#pragma unroll
  for (int i = 0; i < 4; ++i) {
    int m = m0 + (ty << 2) + i;
    int b = m >> 10, nt = m & 1023;
    size_t row = (size_t)b * NTOK + 1 + nt;
#pragma unroll
    for (int j = 0; j < 4; ++j) {
      int n = n0 + (tx << 2) + j;
      scene[row * E_DIM + n] = acc[i][j] + bias[n] + pos[(size_t)(1 + nt) * E_DIM + n];
    }
  }
}

__global__ void scene_cls(const float* __restrict__ cls, const float* __restrict__ pos,
                          float* __restrict__ scene) {
  int b = blockIdx.x;
  for (int e = threadIdx.x; e < E_DIM; e += 256)
    scene[(size_t)b * NTOK * E_DIM + e] = cls[e] + pos[e];
}

__global__ __launch_bounds__(256) void ln_rows(const float* __restrict__ in, float* __restrict__ out) {
  __shared__ float red[256];
  int r = blockIdx.x, tid = threadIdx.x;
  const float* x = in + (size_t)r * E_DIM;
  float a0 = x[tid], a1 = x[tid + 256], a2 = x[tid + 512];
  float mean = block_reduce_sum(a0 + a1 + a2, red) * (1.f / 768.f);
  float d0 = a0 - mean, d1 = a1 - mean, d2 = a2 - mean;
  float var = block_reduce_sum(d0 * d0 + d1 * d1 + d2 * d2, red) * (1.f / 768.f);
  float rinv = rsqrtf(var + 1e-5f);
  float* o = out + (size_t)r * E_DIM;
  o[tid] = d0 * rinv; o[tid + 256] = d1 * rinv; o[tid + 512] = d2 * rinv;
}

__global__ __launch_bounds__(256) void tgt_init(
    const float* __restrict__ tmask, const float* __restrict__ W,
    const float* __restrict__ bias, const float* __restrict__ cls,
    const float* __restrict__ tpos, float* __restrict__ tq) {
  int b = blockIdx.x, tid = threadIdx.x;
  for (int e = tid; e < E_DIM; e += 256)
    tq[(size_t)(b * 2) * E_DIM + e] = cls[e] + tpos[e];
  const float* tm = tmask + (size_t)b * P2;
  for (int e = tid; e < E_DIM; e += 256) {
    const float* wr = W + (size_t)e * P2;
    float s = 0.f;
    for (int k = 0; k < P2; k += 4) {
      float4 w4 = *(const float4*)&wr[k];
      float4 t4 = *(const float4*)&tm[k];
      s += w4.x * t4.x + w4.y * t4.y + w4.z * t4.z + w4.w * t4.w;
    }
    tq[(size_t)(b * 2 + 1) * E_DIM + e] = s + bias[e] + tpos[E_DIM + e];
  }
}

__global__ void prep_m(const float* __restrict__ Wq, const float* __restrict__ Wk,
                       float* __restrict__ Mb) {
  int l = blockIdx.y;
  int idx = blockIdx.x * 256 + threadIdx.x;
  int d = idx >> 6, dp = idx & 63;
  const float* wq = Wq + l * 4096;
  const float* wk = Wk + l * 4096;
  float s = 0.f;
#pragma unroll 8
  for (int e = 0; e < 64; ++e) s += wq[e * 64 + d] * wk[e * 64 + dp];
  Mb[l * 4096 + idx] = s;
}

// all layers at once: Wvo[l][e', h*64+d] = sum_ev Wv[l][ev,d] * Wo[l][e', h*64+ev]
__global__ void prep_wvo(const float* __restrict__ Wv, const float* __restrict__ Wo,
                         float* __restrict__ Wvo) {
  int l = blockIdx.y;
  int idx = blockIdx.x * 256 + threadIdx.x;  // over 768*768
  int ep = idx / 768, hd = idx % 768;
  int h = hd >> 6, d = hd & 63;
  const float* wv = Wv + (size_t)l * 4096;
  const float* wo = Wo + (size_t)l * 768 * 768 + (size_t)ep * 768 + h * 64;
  float s = 0.f;
#pragma unroll 8
  for (int ev = 0; ev < 64; ++ev) s += wv[ev * 64 + d] * wo[ev];
  Wvo[(size_t)l * 589824 + idx] = s;
}

__global__ __launch_bounds__(256) void qln_qm(
    const float* __restrict__ tq, const float* __restrict__ g1,
    const float* __restrict__ b1, const float* __restrict__ Mb, int l,
    float* __restrict__ qMg, float* __restrict__ qMb) {
  __shared__ float q[768];
  __shared__ float qm[768];
  __shared__ float red[256];
  int r = blockIdx.x, tid = threadIdx.x;
  const float* x = tq + (size_t)r * E_DIM;
  float a0 = x[tid], a1 = x[tid + 256], a2 = x[tid + 512];
  float mean = block_reduce_sum(a0 + a1 + a2, red) * (1.f / 768.f);
  float d0 = a0 - mean, d1 = a1 - mean, d2 = a2 - mean;
  float var = block_reduce_sum(d0 * d0 + d1 * d1 + d2 * d2, red) * (1.f / 768.f);
  float rinv = rsqrtf(var + 1e-5f);
  const float* gl = g1 + l * E_DIM;
  const float* bl = b1 + l * E_DIM;
  q[tid] = d0 * rinv * gl[tid] + bl[tid];
  q[tid + 256] = d1 * rinv * gl[tid + 256] + bl[tid + 256];
  q[tid + 512] = d2 * rinv * gl[tid + 512] + bl[tid + 512];
  __syncthreads();
  const float* M = Mb + l * 4096;
  const float inv_scale = rsqrtf(768.f);
  for (int o = tid; o < 768; o += 256) {
    int h = o >> 6, dp = o & 63;
    const float* qh = q + h * 64;
    float s = 0.f;
#pragma unroll 8
    for (int d = 0; d < 64; ++d) s += qh[d] * M[d * 64 + dp];
    qm[o] = s;
    qMg[(size_t)r * E_DIM + o] = s * gl[o] * inv_scale;
  }
  __syncthreads();
  if (tid < NHEADS) {
    float acc = 0.f;
#pragma unroll 8
    for (int dp = 0; dp < 64; ++dp) acc += qm[tid * 64 + dp] * bl[tid * 64 + dp];
    qMb[r * NHEADS + tid] = acc * inv_scale;
  }
}

// fused energy + softmax + ctx; one block per (b,h), both targets.
// energy pass coalesced: 16 lanes x float4 cover one token row (256B contig).
__global__ __launch_bounds__(256) void attn_kernel(
    const float* __restrict__ ns, const float* __restrict__ qMg,
    const float* __restrict__ qMb, const float* __restrict__ g1,
    const float* __restrict__ b1, int l, float* __restrict__ ctx) {
  __shared__ float e0[NTOK], e1[NTOK];
  __shared__ float qg0[64], qg1[64];
  __shared__ float red[256];
  __shared__ float cp[8][64];
  int b = blockIdx.x / NHEADS;
  int h = blockIdx.x % NHEADS;
  int tid = threadIdx.x;
  int r0 = b * 2, r1 = r0 + 1;
  if (tid < 64) {
    qg0[tid] = qMg[(size_t)r0 * E_DIM + h * 64 + tid];
    qg1[tid] = qMg[(size_t)r1 * E_DIM + h * 64 + tid];
  }
  __syncthreads();
  float qb0 = qMb[r0 * NHEADS + h], qb1 = qMb[r1 * NHEADS + h];
  const float* nsb = ns + (size_t)b * NTOK * E_DIM + h * 64;
  // energy: token group = tid>>4 (16 tokens/iter across block), d-slice = (tid&15)*4
  int kk = tid >> 4;
  int dg = (tid & 15) << 2;
  float4 q0v = *(float4*)&qg0[dg];
  float4 q1v = *(float4*)&qg1[dg];
  for (int k = kk; k < NTOK; k += 16) {
    float4 v = *(const float4*)(nsb + (size_t)k * E_DIM + dg);
    float p0 = v.x * q0v.x + v.y * q0v.y + v.z * q0v.z + v.w * q0v.w;
    float p1 = v.x * q1v.x + v.y * q1v.y + v.z * q1v.z + v.w * q1v.w;
#pragma unroll
    for (int off = 8; off; off >>= 1) {
      p0 += __shfl_xor(p0, off, 16);
      p1 += __shfl_xor(p1, off, 16);
    }
    if ((tid & 15) == 0) { e0[k] = p0 + qb0; e1[k] = p1 + qb1; }
  }
  __syncthreads();
  float mx0 = -1e30f, mx1 = -1e30f;
  for (int k = tid; k < NTOK; k += 256) {
    mx0 = fmaxf(mx0, e0[k]); mx1 = fmaxf(mx1, e1[k]);
  }
  red[tid] = mx0; __syncthreads();
  for (int s = 128; s > 0; s >>= 1) { if (tid < s) red[tid] = fmaxf(red[tid], red[tid + s]); __syncthreads(); }
  float M0 = red[0]; __syncthreads();
  red[tid] = mx1; __syncthreads();
  for (int s = 128; s > 0; s >>= 1) { if (tid < s) red[tid] = fmaxf(red[tid], red[tid + s]); __syncthreads(); }
  float M1 = red[0]; __syncthreads();
  float s0 = 0.f, s1 = 0.f;
  for (int k = tid; k < NTOK; k += 256) {
    float p0 = expf(e0[k] - M0); e0[k] = p0; s0 += p0;
    float p1 = expf(e1[k] - M1); e1[k] = p1; s1 += p1;
  }
  float S0 = block_reduce_sum(s0, red);
  float S1 = block_reduce_sum(s1, red);
  float inv0 = 1.f / S0, inv1 = 1.f / S1;
  int d = tid & 63, grp = tid >> 6;
  float a0 = 0.f, a1 = 0.f;
  for (int k = grp; k < NTOK; k += 4) {
    float v = nsb[(size_t)k * E_DIM + d];
    a0 += e0[k] * v;
    a1 += e1[k] * v;
  }
  cp[grp][d] = a0;
  cp[4 + grp][d] = a1;
  __syncthreads();
  if (tid < 128) {
    int t = tid >> 6, dd = tid & 63;
    int o = h * 64 + dd;
    float gg = g1[l * E_DIM + o], bb = b1[l * E_DIM + o];
    if (t == 0) {
      float s = (cp[0][dd] + cp[1][dd] + cp[2][dd] + cp[3][dd]) * inv0;
      ctx[(size_t)r0 * E_DIM + o] = s * gg + bb;
    } else {
      float s = (cp[4][dd] + cp[5][dd] + cp[6][dd] + cp[7][dd]) * inv1;
      ctx[(size_t)r1 * E_DIM + o] = s * gg + bb;
    }
  }
}

// ---------------- skinny GEMM (M=64): partial over k-chunk ----------------
// out_part[s][m][n] = sum_{k in chunk s} X[m,k]*W[n,k]
// grid (N/64, KSPLIT), block 256. kchunk % 16 == 0.
__global__ __launch_bounds__(256) void skinny_part(
    const float* __restrict__ X, int K, const float* __restrict__ W,
    int kchunk, float* __restrict__ part, int N) {
  __shared__ float Xs[16][64];
  __shared__ float Ws[16][64];
  int tid = threadIdx.x;
  int n0 = blockIdx.x * 64;
  int s = blockIdx.y;
  int kbeg = s * kchunk;
  int lr = tid >> 2;
  int lk = (tid & 3) << 2;
  int ty = tid >> 4, tx = tid & 15;
  float acc[4][4] = {};
  for (int k0 = kbeg; k0 < kbeg + kchunk; k0 += 16) {
    float4 xv = *(const float4*)(X + (size_t)lr * K + k0 + lk);
    float4 wv = *(const float4*)(W + (size_t)(n0 + lr) * K + k0 + lk);
    Xs[lk + 0][lr] = xv.x; Xs[lk + 1][lr] = xv.y; Xs[lk + 2][lr] = xv.z; Xs[lk + 3][lr] = xv.w;
    Ws[lk + 0][lr] = wv.x; Ws[lk + 1][lr] = wv.y; Ws[lk + 2][lr] = wv.z; Ws[lk + 3][lr] = wv.w;
    __syncthreads();
#pragma unroll
    for (int kk = 0; kk < 16; ++kk) {
      float4 a4 = *(const float4*)&Xs[kk][ty << 2];
      float4 b4 = *(const float4*)&Ws[kk][tx << 2];
      float av[4] = {a4.x, a4.y, a4.z, a4.w};
      float bv[4] = {b4.x, b4.y, b4.z, b4.w};
#pragma unroll
      for (int i = 0; i < 4; ++i)
#pragma unroll
        for (int j = 0; j < 4; ++j) acc[i][j] += av[i] * bv[j];
    }
    __syncthreads();
  }
#pragma unroll
  for (int i = 0; i < 4; ++i) {
    int m = (ty << 2) + i;
    float4 o4 = make_float4(acc[i][0], acc[i][1], acc[i][2], acc[i][3]);
    *(float4*)&part[((size_t)s * 64 + m) * N + n0 + (tx << 2)] = o4;
  }
}

// reduce partials + bias (+relu). one block per m row.
__global__ __launch_bounds__(256) void reduce_bias(
    const float* __restrict__ part, int S, int N,
    const float* __restrict__ bias, int relu, float* __restrict__ out) {
  int m = blockIdx.x;
  for (int n = threadIdx.x; n < N; n += 256) {
    float s = 0.f;
    for (int i = 0; i < S; ++i) s += part[((size_t)i * 64 + m) * N + n];
    s += bias[n];
    if (relu) s = fmaxf(s, 0.f);
    out[(size_t)m * N + n] = s;
  }
}

// reduce partials + bias + residual + LN (N=768). one block per m row.
__global__ __launch_bounds__(256) void reduce_ln(
    const float* __restrict__ part, int S, const float* __restrict__ bias,
    const float* __restrict__ res, const float* __restrict__ g,
    const float* __restrict__ bsh, float* __restrict__ out) {
  __shared__ float red[256];
  int m = blockIdx.x, tid = threadIdx.x;
  float t[3];
#pragma unroll
  for (int c = 0; c < 3; ++c) {
    int n = tid + c * 256;
    float s = 0.f;
    for (int i = 0; i < S; ++i) s += part[((size_t)i * 64 + m) * 768 + n];
    t[c] = s + bias[n] + res[(size_t)m * 768 + n];
  }
  float mean = block_reduce_sum(t[0] + t[1] + t[2], red) * (1.f / 768.f);
  float d0 = t[0] - mean, d1 = t[1] - mean, d2 = t[2] - mean;
  float var = block_reduce_sum(d0 * d0 + d1 * d1 + d2 * d2, red) * (1.f / 768.f);
  float rinv = rsqrtf(var + 1e-5f);
  out[(size_t)m * 768 + tid] = d0 * rinv * g[tid] + bsh[tid];
  out[(size_t)m * 768 + tid + 256] = d1 * rinv * g[tid + 256] + bsh[tid + 256];
  out[(size_t)m * 768 + tid + 512] = d2 * rinv * g[tid + 512] + bsh[tid + 512];
}

// mean over 2 target tokens, zero-padded to 64 rows for skinny GEMM
__global__ void mean_rows(const float* __restrict__ tq, float* __restrict__ xm) {
  int idx = blockIdx.x * 256 + threadIdx.x;  // 64*768
  int b = idx / E_DIM, e = idx % E_DIM;
  xm[idx] = (b < 32)
      ? 0.5f * (tq[(size_t)(b * 2) * E_DIM + e] + tq[(size_t)(b * 2 + 1) * E_DIM + e])
      : 0.f;
}

__global__ __launch_bounds__(256) void top5_onehot(const float* __restrict__ logits,
                                                   float* __restrict__ out) {
  __shared__ float v[1024];
  __shared__ float bv[256];
  __shared__ int bi[256];
  int b = blockIdx.x, tid = threadIdx.x;
  for (int i = tid; i < 1024; i += 256) v[i] = logits[(size_t)b * 1024 + i];
  float* ob = out + (size_t)b * 5 * NTOK;
  for (int i = tid; i < 5 * NTOK; i += 256) ob[i] = 0.f;
  __syncthreads();
  for (int it = 0; it < 5; ++it) {
    float best = -1e38f;
    int bidx = 0x7fffffff;
    for (int i = tid; i < 1024; i += 256) {
      float x = v[i];
      if (x > best || (x == best && i < bidx)) { best = x; bidx = i; }
    }
    bv[tid] = best; bi[tid] = bidx;
    __syncthreads();
    for (int s = 128; s > 0; s >>= 1) {
      if (tid < s) {
        if (bv[tid + s] > bv[tid] || (bv[tid + s] == bv[tid] && bi[tid + s] < bi[tid])) {
          bv[tid] = bv[tid + s]; bi[tid] = bi[tid + s];
        }
      }
      __syncthreads();
    }
    if (tid == 0) {
      ob[it * NTOK + bi[0]] = 1.0f;
      v[bi[0]] = -1e38f;
    }
    __syncthreads();
  }
}

extern "C" void kernel_launch(void* const* d_in, const int* in_sizes, int n_in,
                              void* d_out, int out_size, void* d_ws, size_t ws_size,
                              hipStream_t stream) {
  const float* scene_masks = (const float*)d_in[0];
  const float* target_mask = (const float*)d_in[1];
  const float* emb_W = (const float*)d_in[2];
  const float* emb_b = (const float*)d_in[3];
  const float* class_embed = (const float*)d_in[4];
  const float* scene_pos = (const float*)d_in[5];
  const float* target_pos = (const float*)d_in[6];
  const float* ln1_g = (const float*)d_in[7];
  const float* ln1_b = (const float*)d_in[8];
  const float* ln2_g = (const float*)d_in[9];
  const float* ln2_b = (const float*)d_in[10];
  const float* Wq = (const float*)d_in[11];
  const float* Wk = (const float*)d_in[12];
  const float* Wv = (const float*)d_in[13];
  const float* Wo = (const float*)d_in[14];
  const float* bo = (const float*)d_in[15];
  const float* W1 = (const float*)d_in[16];
  const float* fb1 = (const float*)d_in[17];
  const float* W2 = (const float*)d_in[18];
  const float* fb2 = (const float*)d_in[19];
  const float* mlp_W = (const float*)d_in[20];
  const float* mlp_b = (const float*)d_in[21];
  float* out = (float*)d_out;

  float* ws = (float*)d_ws;
  float* scene = ws;                       // 25190400
  float* Mbuf = scene + 25190400;          // 49152
  float* Wvo = Mbuf + 49152;               // 12*589824 = 7077888
  float* tq = Wvo + 7077888;               // 49152
  float* qMg = tq + 49152;                 // 49152
  float* qMb = qMg + 49152;                // 768
  float* ctxf = qMb + 768;                 // 49152
  float* xbuf = ctxf + 49152;              // 49152
  float* h1 = xbuf + 49152;                // 196608
  float* xm = h1 + 196608;                 // 49152 (64x768, padded)
  float* logits = xm + 49152;              // 65536 (64x1024)
  float* part = logits + 65536;            // 786432 max

  // ---- setup ----
  embed_gemm<<<dim3(12, 512), 256, 0, stream>>>(scene_masks, emb_W, emb_b, scene_pos, scene);
  scene_cls<<<32, 256, 0, stream>>>(class_embed, scene_pos, scene);
  ln_rows<<<32 * NTOK, 256, 0, stream>>>(scene, scene);
  tgt_init<<<32, 256, 0, stream>>>(target_mask, emb_W, emb_b, class_embed, target_pos, tq);
  prep_m<<<dim3(16, 12), 256, 0, stream>>>(Wq, Wk, Mbuf);
  prep_wvo<<<dim3(2304, 12), 256, 0, stream>>>(Wv, Wo, Wvo);

  // ---- 12 transformer blocks on the 2-token target path ----
  for (int l = 0; l < LAYERS; ++l) {
    qln_qm<<<64, 256, 0, stream>>>(tq, ln1_g, ln1_b, Mbuf, l, qMg, qMb);
    attn_kernel<<<32 * NHEADS, 256, 0, stream>>>(scene, qMg, qMb, ln1_g, ln1_b, l, ctxf);
    // out2 = ctx @ Wvo_l^T + bo; x = LN(out2 + tq)
    skinny_part<<<dim3(12, 8), 256, 0, stream>>>(ctxf, 768, Wvo + (size_t)l * 589824, 96, part, 768);
    reduce_ln<<<64, 256, 0, stream>>>(part, 8, bo + l * 768, tq,
                                      ln1_g + l * 768, ln1_b + l * 768, xbuf);
    // h1 = relu(x @ W1^T + b1)
    skinny_part<<<dim3(48, 4), 256, 0, stream>>>(xbuf, 768, W1 + (size_t)l * FF_DIM * 768, 192, part, FF_DIM);
    reduce_bias<<<64, 256, 0, stream>>>(part, 4, FF_DIM, fb1 + l * FF_DIM, 1, h1);
    // tq = LN(h1 @ W2^T + b2 + x)
    skinny_part<<<dim3(12, 16), 256, 0, stream>>>(h1, FF_DIM, W2 + (size_t)l * 768 * FF_DIM, 192, part, 768);
    reduce_ln<<<64, 256, 0, stream>>>(part, 16, fb2 + l * 768, xbuf,
                                      ln2_g + l * 768, ln2_b + l * 768, tq);
  }

  // ---- head ----
  mean_rows<<<192, 256, 0, stream>>>(tq, xm);
  skinny_part<<<dim3(16, 4), 256, 0, stream>>>(xm, 768, mlp_W, 192, part, 1024);
  reduce_bias<<<64, 256, 0, stream>>>(part, 4, 1024, mlp_b, 0, logits);
  top5_onehot<<<32, 256, 0, stream>>>(logits, out);
}

// Round 3
// 2087.990 us; speedup vs baseline: 3.7086x; 1.4112x over previous
//
#include <hip/hip_runtime.h>
#include <math.h>

#define E_DIM 768
#define NTOK 1025
#define B_DIM 32
#define NHEADS 12
#define HDIM 64
#define LAYERS 12
#define FF_DIM 3072
#define P2 576

// ---------------- helpers ----------------
__device__ __forceinline__ float block_reduce_sum(float v, float* red) {
  int tid = threadIdx.x;
  red[tid] = v;
  __syncthreads();
#pragma unroll
  for (int s = 128; s > 0; s >>= 1) {
    if (tid < s) red[tid] += red[tid + s];
    __syncthreads();
  }
  float r = red[0];
  __syncthreads();
  return r;
}

// ---------------- embed GEMM: 128x128 tile, 8x8 acc/thread ----------------
// A [32768,576], W [768,576]; scene[b,1+nt,e] = A@W^T + bias + pos
__global__ __launch_bounds__(256) void embed_gemm(
    const float* __restrict__ A, const float* __restrict__ W,
    const float* __restrict__ bias, const float* __restrict__ pos,
    float* __restrict__ scene) {
  __shared__ float Xs[16][132];
  __shared__ float Ws[16][132];
  int tid = threadIdx.x;
  int n0 = blockIdx.x * 128;  // 6 tiles over 768
  int m0 = blockIdx.y * 128;  // 256 tiles over 32768
  int lr = tid >> 2;           // 0..63
  int lk = (tid & 3) << 2;     // 0,4,8,12
  int ty = tid >> 4, tx = tid & 15;
  float acc[8][8] = {};
  for (int k0 = 0; k0 < P2; k0 += 16) {
    float4 x0 = *(const float4*)(A + (size_t)(m0 + lr) * P2 + k0 + lk);
    float4 x1 = *(const float4*)(A + (size_t)(m0 + 64 + lr) * P2 + k0 + lk);
    float4 w0 = *(const float4*)(W + (size_t)(n0 + lr) * P2 + k0 + lk);
    float4 w1 = *(const float4*)(W + (size_t)(n0 + 64 + lr) * P2 + k0 + lk);
    __syncthreads();
    Xs[lk + 0][lr] = x0.x; Xs[lk + 1][lr] = x0.y; Xs[lk + 2][lr] = x0.z; Xs[lk + 3][lr] = x0.w;
    Xs[lk + 0][64 + lr] = x1.x; Xs[lk + 1][64 + lr] = x1.y; Xs[lk + 2][64 + lr] = x1.z; Xs[lk + 3][64 + lr] = x1.w;
    Ws[lk + 0][lr] = w0.x; Ws[lk + 1][lr] = w0.y; Ws[lk + 2][lr] = w0.z; Ws[lk + 3][lr] = w0.w;
    Ws[lk + 0][64 + lr] = w1.x; Ws[lk + 1][64 + lr] = w1.y; Ws[lk + 2][64 + lr] = w1.z; Ws[lk + 3][64 + lr] = w1.w;
    __syncthreads();
#pragma unroll
    for (int kk = 0; kk < 16; ++kk) {
      float4 a0 = *(const float4*)&Xs[kk][ty << 2];
      float4 a1 = *(const float4*)&Xs[kk][64 + (ty << 2)];
      float4 b0 = *(const float4*)&Ws[kk][tx << 2];
      float4 b1 = *(const float4*)&Ws[kk][64 + (tx << 2)];
      float av[8] = {a0.x, a0.y, a0.z, a0.w, a1.x, a1.y, a1.z, a1.w};
      float bv[8] = {b0.x, b0.y, b0.z, b0.w, b1.x, b1.y, b1.z, b1.w};
#pragma unroll
      for (int i = 0; i < 8; ++i)
#pragma unroll
        for (int j = 0; j < 8; ++j) acc[i][j] += av[i] * bv[j];
    }
  }
#pragma unroll
  for (int i = 0; i < 8; ++i) {
    int mloc = (i < 4) ? ((ty << 2) + i) : (64 + (ty << 2) + i - 4);
    int m = m0 + mloc;
    int b = m >> 10, nt = m & 1023;
    size_t row = ((size_t)b * NTOK + 1 + nt) * E_DIM;
    size_t prow = (size_t)(1 + nt) * E_DIM;
#pragma unroll
    for (int half = 0; half < 2; ++half) {
      int n = n0 + half * 64 + (tx << 2);
      float4 o4;
      o4.x = acc[i][half * 4 + 0] + bias[n + 0] + pos[prow + n + 0];
      o4.y = acc[i][half * 4 + 1] + bias[n + 1] + pos[prow + n + 1];
      o4.z = acc[i][half * 4 + 2] + bias[n + 2] + pos[prow + n + 2];
      o4.w = acc[i][half * 4 + 3] + bias[n + 3] + pos[prow + n + 3];
      *(float4*)&scene[row + n] = o4;
    }
  }
}

__global__ void scene_cls(const float* __restrict__ cls, const float* __restrict__ pos,
                          float* __restrict__ scene) {
  int b = blockIdx.x;
  for (int e = threadIdx.x; e < E_DIM; e += 256)
    scene[(size_t)b * NTOK * E_DIM + e] = cls[e] + pos[e];
}

__global__ __launch_bounds__(256) void ln_rows(const float* __restrict__ in, float* __restrict__ out) {
  __shared__ float red[256];
  int r = blockIdx.x, tid = threadIdx.x;
  const float* x = in + (size_t)r * E_DIM;
  float a0 = x[tid], a1 = x[tid + 256], a2 = x[tid + 512];
  float mean = block_reduce_sum(a0 + a1 + a2, red) * (1.f / 768.f);
  float d0 = a0 - mean, d1 = a1 - mean, d2 = a2 - mean;
  float var = block_reduce_sum(d0 * d0 + d1 * d1 + d2 * d2, red) * (1.f / 768.f);
  float rinv = rsqrtf(var + 1e-5f);
  float* o = out + (size_t)r * E_DIM;
  o[tid] = d0 * rinv; o[tid + 256] = d1 * rinv; o[tid + 512] = d2 * rinv;
}

__global__ __launch_bounds__(256) void tgt_init(
    const float* __restrict__ tmask, const float* __restrict__ W,
    const float* __restrict__ bias, const float* __restrict__ cls,
    const float* __restrict__ tpos, float* __restrict__ tq) {
  int b = blockIdx.x, tid = threadIdx.x;
  for (int e = tid; e < E_DIM; e += 256)
    tq[(size_t)(b * 2) * E_DIM + e] = cls[e] + tpos[e];
  const float* tm = tmask + (size_t)b * P2;
  for (int e = tid; e < E_DIM; e += 256) {
    const float* wr = W + (size_t)e * P2;
    float s = 0.f;
    for (int k = 0; k < P2; k += 4) {
      float4 w4 = *(const float4*)&wr[k];
      float4 t4 = *(const float4*)&tm[k];
      s += w4.x * t4.x + w4.y * t4.y + w4.z * t4.z + w4.w * t4.w;
    }
    tq[(size_t)(b * 2 + 1) * E_DIM + e] = s + bias[e] + tpos[E_DIM + e];
  }
}

__global__ void prep_m(const float* __restrict__ Wq, const float* __restrict__ Wk,
                       float* __restrict__ Mb) {
  int l = blockIdx.y;
  int idx = blockIdx.x * 256 + threadIdx.x;
  int d = idx >> 6, dp = idx & 63;
  const float* wq = Wq + l * 4096;
  const float* wk = Wk + l * 4096;
  float s = 0.f;
#pragma unroll 8
  for (int e = 0; e < 64; ++e) s += wq[e * 64 + d] * wk[e * 64 + dp];
  Mb[l * 4096 + idx] = s;
}

__global__ void prep_wvo(const float* __restrict__ Wv, const float* __restrict__ Wo,
                         float* __restrict__ Wvo) {
  int l = blockIdx.y;
  int idx = blockIdx.x * 256 + threadIdx.x;
  int ep = idx / 768, hd = idx % 768;
  int h = hd >> 6, d = hd & 63;
  const float* wv = Wv + (size_t)l * 4096;
  const float* wo = Wo + (size_t)l * 768 * 768 + (size_t)ep * 768 + h * 64;
  float s = 0.f;
#pragma unroll 8
  for (int ev = 0; ev < 64; ++ev) s += wv[ev * 64 + d] * wo[ev];
  Wvo[(size_t)l * 589824 + idx] = s;
}

// standalone qln (layer 0 only)
__global__ __launch_bounds__(256) void qln_qm(
    const float* __restrict__ tq, const float* __restrict__ g1,
    const float* __restrict__ b1, const float* __restrict__ Mb, int l,
    float* __restrict__ qMg, float* __restrict__ qMb) {
  __shared__ float q[768];
  __shared__ float qm[768];
  __shared__ float red[256];
  int r = blockIdx.x, tid = threadIdx.x;
  const float* x = tq + (size_t)r * E_DIM;
  float a0 = x[tid], a1 = x[tid + 256], a2 = x[tid + 512];
  float mean = block_reduce_sum(a0 + a1 + a2, red) * (1.f / 768.f);
  float d0 = a0 - mean, d1 = a1 - mean, d2 = a2 - mean;
  float var = block_reduce_sum(d0 * d0 + d1 * d1 + d2 * d2, red) * (1.f / 768.f);
  float rinv = rsqrtf(var + 1e-5f);
  const float* gl = g1 + l * E_DIM;
  const float* bl = b1 + l * E_DIM;
  q[tid] = d0 * rinv * gl[tid] + bl[tid];
  q[tid + 256] = d1 * rinv * gl[tid + 256] + bl[tid + 256];
  q[tid + 512] = d2 * rinv * gl[tid + 512] + bl[tid + 512];
  __syncthreads();
  const float* M = Mb + l * 4096;
  const float inv_scale = rsqrtf(768.f);
  for (int o = tid; o < 768; o += 256) {
    int h = o >> 6, dp = o & 63;
    const float* qh = q + h * 64;
    float s = 0.f;
#pragma unroll 8
    for (int d = 0; d < 64; ++d) s += qh[d] * M[d * 64 + dp];
    qm[o] = s;
    qMg[(size_t)r * E_DIM + o] = s * gl[o] * inv_scale;
  }
  __syncthreads();
  if (tid < NHEADS) {
    float acc = 0.f;
#pragma unroll 8
    for (int dp = 0; dp < 64; ++dp) acc += qm[tid * 64 + dp] * bl[tid * 64 + dp];
    qMb[r * NHEADS + tid] = acc * inv_scale;
  }
}

// ---------------- flash attention: single pass over scene ----------------
// one block per (b,h); 16 token-groups x 16 d-lanes; online softmax, chunk=272
#define ACH 272
__global__ __launch_bounds__(256) void attn_flash(
    const float* __restrict__ ns, const float* __restrict__ qMg,
    const float* __restrict__ qMb, const float* __restrict__ g1,
    const float* __restrict__ b1, int l, float* __restrict__ ctx) {
  __shared__ float red[256];
  __shared__ float sred[2][16];
  __shared__ float cred[2][16][64];
  int b = blockIdx.x / NHEADS;
  int h = blockIdx.x % NHEADS;
  int tid = threadIdx.x;
  int g = tid >> 4;     // token group
  int lane = tid & 15;  // d-slice
  int r0 = b * 2, r1 = r0 + 1;
  const float* nsb = ns + (size_t)b * NTOK * E_DIM + h * 64;
  float4 q0v = *(const float4*)(qMg + (size_t)r0 * E_DIM + h * 64 + lane * 4);
  float4 q1v = *(const float4*)(qMg + (size_t)r1 * E_DIM + h * 64 + lane * 4);
  float qb0 = qMb[r0 * NHEADS + h], qb1 = qMb[r1 * NHEADS + h];
  float m = -1e30f, s0 = 0.f, s1 = 0.f;
  float4 c0 = {0, 0, 0, 0}, c1 = {0, 0, 0, 0};
  float4 v[17];
  float e0a[17], e1a[17];
  for (int cb = 0; cb < NTOK; cb += ACH) {
    int ntk = NTOK - cb; if (ntk > ACH) ntk = ACH;
    int cnt = (ntk - g + 15) >> 4;  // tokens this group handles (uniform per group)
    float mloc = -1e30f;
#pragma unroll
    for (int i = 0; i < 17; ++i) {
      if (i < cnt) {
        int k = cb + g + (i << 4);
        float4 vv = *(const float4*)(nsb + (size_t)k * E_DIM + lane * 4);
        v[i] = vv;
        float p0 = vv.x * q0v.x + vv.y * q0v.y + vv.z * q0v.z + vv.w * q0v.w;
        float p1 = vv.x * q1v.x + vv.y * q1v.y + vv.z * q1v.z + vv.w * q1v.w;
#pragma unroll
        for (int off = 8; off; off >>= 1) {
          p0 += __shfl_xor(p0, off, 16);
          p1 += __shfl_xor(p1, off, 16);
        }
        float e0 = p0 + qb0, e1 = p1 + qb1;
        e0a[i] = e0; e1a[i] = e1;
        mloc = fmaxf(mloc, fmaxf(e0, e1));
      }
    }
    red[tid] = mloc;
    __syncthreads();
#pragma unroll
    for (int s = 128; s > 0; s >>= 1) {
      if (tid < s) red[tid] = fmaxf(red[tid], red[tid + s]);
      __syncthreads();
    }
    float mnew = fmaxf(m, red[0]);
    __syncthreads();
    if (mnew > m) {
      float f = expf(m - mnew);
      s0 *= f; s1 *= f;
      c0.x *= f; c0.y *= f; c0.z *= f; c0.w *= f;
      c1.x *= f; c1.y *= f; c1.z *= f; c1.w *= f;
      m = mnew;
    }
#pragma unroll
    for (int i = 0; i < 17; ++i) {
      if (i < cnt) {
        float p0 = expf(e0a[i] - m);
        float p1 = expf(e1a[i] - m);
        s0 += p0; s1 += p1;
        c0.x += p0 * v[i].x; c0.y += p0 * v[i].y; c0.z += p0 * v[i].z; c0.w += p0 * v[i].w;
        c1.x += p1 * v[i].x; c1.y += p1 * v[i].y; c1.z += p1 * v[i].z; c1.w += p1 * v[i].w;
      }
    }
  }
  if (lane == 0) { sred[0][g] = s0; sred[1][g] = s1; }
  *(float4*)&cred[0][g][lane * 4] = c0;
  *(float4*)&cred[1][g][lane * 4] = c1;
  __syncthreads();
  if (tid < 128) {
    int t = tid >> 6, d = tid & 63;
    float stot = 0.f, cs = 0.f;
#pragma unroll
    for (int gg = 0; gg < 16; ++gg) { stot += sred[t][gg]; cs += cred[t][gg][d]; }
    float inv = 1.f / stot;
    int o = h * 64 + d;
    ctx[(size_t)(r0 + t) * E_DIM + o] = cs * inv * g1[l * E_DIM + o] + b1[l * E_DIM + o];
  }
}

// ---------------- skinny GEMM (M=64) partial over k-chunk ----------------
__global__ __launch_bounds__(256) void skinny_part(
    const float* __restrict__ X, int K, const float* __restrict__ W,
    int kchunk, float* __restrict__ part, int N) {
  __shared__ float Xs[16][64];
  __shared__ float Ws[16][64];
  int tid = threadIdx.x;
  int n0 = blockIdx.x * 64;
  int s = blockIdx.y;
  int kbeg = s * kchunk;
  int lr = tid >> 2;
  int lk = (tid & 3) << 2;
  int ty = tid >> 4, tx = tid & 15;
  float acc[4][4] = {};
  for (int k0 = kbeg; k0 < kbeg + kchunk; k0 += 16) {
    float4 xv = *(const float4*)(X + (size_t)lr * K + k0 + lk);
    float4 wv = *(const float4*)(W + (size_t)(n0 + lr) * K + k0 + lk);
    __syncthreads();
    Xs[lk + 0][lr] = xv.x; Xs[lk + 1][lr] = xv.y; Xs[lk + 2][lr] = xv.z; Xs[lk + 3][lr] = xv.w;
    Ws[lk + 0][lr] = wv.x; Ws[lk + 1][lr] = wv.y; Ws[lk + 2][lr] = wv.z; Ws[lk + 3][lr] = wv.w;
    __syncthreads();
#pragma unroll
    for (int kk = 0; kk < 16; ++kk) {
      float4 a4 = *(const float4*)&Xs[kk][ty << 2];
      float4 b4 = *(const float4*)&Ws[kk][tx << 2];
      float av[4] = {a4.x, a4.y, a4.z, a4.w};
      float bv[4] = {b4.x, b4.y, b4.z, b4.w};
#pragma unroll
      for (int i = 0; i < 4; ++i)
#pragma unroll
        for (int j = 0; j < 4; ++j) acc[i][j] += av[i] * bv[j];
    }
  }
#pragma unroll
  for (int i = 0; i < 4; ++i) {
    int mm = (ty << 2) + i;
    float4 o4 = make_float4(acc[i][0], acc[i][1], acc[i][2], acc[i][3]);
    *(float4*)&part[((size_t)s * 64 + mm) * N + n0 + (tx << 2)] = o4;
  }
}

__global__ __launch_bounds__(256) void reduce_bias(
    const float* __restrict__ part, int S, int N,
    const float* __restrict__ bias, int relu, float* __restrict__ out) {
  int m = blockIdx.x;
  for (int n = threadIdx.x; n < N; n += 256) {
    float s = 0.f;
    for (int i = 0; i < S; ++i) s += part[((size_t)i * 64 + m) * N + n];
    s += bias[n];
    if (relu) s = fmaxf(s, 0.f);
    out[(size_t)m * N + n] = s;
  }
}

// reduce partials + bias + residual + LN (N=768); optionally fused next-layer qln
__global__ __launch_bounds__(256) void reduce_ln_q(
    const float* __restrict__ part, int S, const float* __restrict__ bias,
    const float* __restrict__ res, const float* __restrict__ g,
    const float* __restrict__ bsh, float* __restrict__ out,
    const float* __restrict__ Mb_next, const float* __restrict__ g1n,
    const float* __restrict__ b1n, float* __restrict__ qMg,
    float* __restrict__ qMb) {
  __shared__ float red[256];
  __shared__ float q[768];
  __shared__ float qm[768];
  int m = blockIdx.x, tid = threadIdx.x;
  float t[3];
#pragma unroll
  for (int c = 0; c < 3; ++c) {
    int n = tid + c * 256;
    float s = 0.f;
    for (int i = 0; i < S; ++i) s += part[((size_t)i * 64 + m) * 768 + n];
    t[c] = s + bias[n] + res[(size_t)m * 768 + n];
  }
  float mean = block_reduce_sum(t[0] + t[1] + t[2], red) * (1.f / 768.f);
  float d0 = t[0] - mean, d1 = t[1] - mean, d2 = t[2] - mean;
  float var = block_reduce_sum(d0 * d0 + d1 * d1 + d2 * d2, red) * (1.f / 768.f);
  float rinv = rsqrtf(var + 1e-5f);
  float y0 = d0 * rinv * g[tid] + bsh[tid];
  float y1 = d1 * rinv * g[tid + 256] + bsh[tid + 256];
  float y2 = d2 * rinv * g[tid + 512] + bsh[tid + 512];
  out[(size_t)m * 768 + tid] = y0;
  out[(size_t)m * 768 + tid + 256] = y1;
  out[(size_t)m * 768 + tid + 512] = y2;
  if (Mb_next) {
    float mean2 = block_reduce_sum(y0 + y1 + y2, red) * (1.f / 768.f);
    float e0 = y0 - mean2, e1 = y1 - mean2, e2 = y2 - mean2;
    float var2 = block_reduce_sum(e0 * e0 + e1 * e1 + e2 * e2, red) * (1.f / 768.f);
    float rinv2 = rsqrtf(var2 + 1e-5f);
    q[tid] = e0 * rinv2 * g1n[tid] + b1n[tid];
    q[tid + 256] = e1 * rinv2 * g1n[tid + 256] + b1n[tid + 256];
    q[tid + 512] = e2 * rinv2 * g1n[tid + 512] + b1n[tid + 512];
    __syncthreads();
    const float inv_scale = rsqrtf(768.f);
    for (int o = tid; o < 768; o += 256) {
      int h = o >> 6, dp = o & 63;
      const float* qh = q + h * 64;
      float s = 0.f;
#pragma unroll 8
      for (int d = 0; d < 64; ++d) s += qh[d] * Mb_next[d * 64 + dp];
      qm[o] = s;
      qMg[(size_t)m * E_DIM + o] = s * g1n[o] * inv_scale;
    }
    __syncthreads();
    if (tid < NHEADS) {
      float acc = 0.f;
#pragma unroll 8
      for (int dp = 0; dp < 64; ++dp) acc += qm[tid * 64 + dp] * b1n[tid * 64 + dp];
      qMb[m * NHEADS + tid] = acc * inv_scale;
    }
  }
}

__global__ void mean_rows(const float* __restrict__ tq, float* __restrict__ xm) {
  int idx = blockIdx.x * 256 + threadIdx.x;
  int b = idx / E_DIM, e = idx % E_DIM;
  xm[idx] = (b < 32)
      ? 0.5f * (tq[(size_t)(b * 2) * E_DIM + e] + tq[(size_t)(b * 2 + 1) * E_DIM + e])
      : 0.f;
}

__global__ __launch_bounds__(256) void top5_onehot(const float* __restrict__ logits,
                                                   float* __restrict__ out) {
  __shared__ float v[1024];
  __shared__ float bv[256];
  __shared__ int bi[256];
  int b = blockIdx.x, tid = threadIdx.x;
  for (int i = tid; i < 1024; i += 256) v[i] = logits[(size_t)b * 1024 + i];
  float* ob = out + (size_t)b * 5 * NTOK;
  for (int i = tid; i < 5 * NTOK; i += 256) ob[i] = 0.f;
  __syncthreads();
  for (int it = 0; it < 5; ++it) {
    float best = -1e38f;
    int bidx = 0x7fffffff;
    for (int i = tid; i < 1024; i += 256) {
      float x = v[i];
      if (x > best || (x == best && i < bidx)) { best = x; bidx = i; }
    }
    bv[tid] = best; bi[tid] = bidx;
    __syncthreads();
    for (int s = 128; s > 0; s >>= 1) {
      if (tid < s) {
        if (bv[tid + s] > bv[tid] || (bv[tid + s] == bv[tid] && bi[tid + s] < bi[tid])) {
          bv[tid] = bv[tid + s]; bi[tid] = bi[tid + s];
        }
      }
      __syncthreads();
    }
    if (tid == 0) {
      ob[it * NTOK + bi[0]] = 1.0f;
      v[bi[0]] = -1e38f;
    }
    __syncthreads();
  }
}

extern "C" void kernel_launch(void* const* d_in, const int* in_sizes, int n_in,
                              void* d_out, int out_size, void* d_ws, size_t ws_size,
                              hipStream_t stream) {
  const float* scene_masks = (const float*)d_in[0];
  const float* target_mask = (const float*)d_in[1];
  const float* emb_W = (const float*)d_in[2];
  const float* emb_b = (const float*)d_in[3];
  const float* class_embed = (const float*)d_in[4];
  const float* scene_pos = (const float*)d_in[5];
  const float* target_pos = (const float*)d_in[6];
  const float* ln1_g = (const float*)d_in[7];
  const float* ln1_b = (const float*)d_in[8];
  const float* ln2_g = (const float*)d_in[9];
  const float* ln2_b = (const float*)d_in[10];
  const float* Wq = (const float*)d_in[11];
  const float* Wk = (const float*)d_in[12];
  const float* Wv = (const float*)d_in[13];
  const float* Wo = (const float*)d_in[14];
  const float* bo = (const float*)d_in[15];
  const float* W1 = (const float*)d_in[16];
  const float* fb1 = (const float*)d_in[17];
  const float* W2 = (const float*)d_in[18];
  const float* fb2 = (const float*)d_in[19];
  const float* mlp_W = (const float*)d_in[20];
  const float* mlp_b = (const float*)d_in[21];
  float* out = (float*)d_out;

  float* ws = (float*)d_ws;
  float* scene = ws;                       // 25190400
  float* Mbuf = scene + 25190400;          // 49152
  float* Wvo = Mbuf + 49152;               // 7077888
  float* tq = Wvo + 7077888;               // 49152
  float* qMg = tq + 49152;                 // 49152
  float* qMb = qMg + 49152;                // 768
  float* ctxf = qMb + 768;                 // 49152
  float* xbuf = ctxf + 49152;              // 49152
  float* h1 = xbuf + 49152;                // 196608
  float* xm = h1 + 196608;                 // 49152
  float* logits = xm + 49152;              // 65536
  float* part = logits + 65536;            // 786432 max

  // ---- setup ----
  embed_gemm<<<dim3(6, 256), 256, 0, stream>>>(scene_masks, emb_W, emb_b, scene_pos, scene);
  scene_cls<<<32, 256, 0, stream>>>(class_embed, scene_pos, scene);
  ln_rows<<<32 * NTOK, 256, 0, stream>>>(scene, scene);
  tgt_init<<<32, 256, 0, stream>>>(target_mask, emb_W, emb_b, class_embed, target_pos, tq);
  prep_m<<<dim3(16, 12), 256, 0, stream>>>(Wq, Wk, Mbuf);
  prep_wvo<<<dim3(2304, 12), 256, 0, stream>>>(Wv, Wo, Wvo);
  qln_qm<<<64, 256, 0, stream>>>(tq, ln1_g, ln1_b, Mbuf, 0, qMg, qMb);

  // ---- 12 transformer blocks ----
  for (int l = 0; l < LAYERS; ++l) {
    attn_flash<<<32 * NHEADS, 256, 0, stream>>>(scene, qMg, qMb, ln1_g, ln1_b, l, ctxf);
    // out2 = ctx @ Wvo_l^T + bo; x = LN1(out2 + tq)
    skinny_part<<<dim3(12, 8), 256, 0, stream>>>(ctxf, 768, Wvo + (size_t)l * 589824, 96, part, 768);
    reduce_ln_q<<<64, 256, 0, stream>>>(part, 8, bo + l * 768, tq,
                                        ln1_g + l * 768, ln1_b + l * 768, xbuf,
                                        nullptr, nullptr, nullptr, nullptr, nullptr);
    // h1 = relu(x @ W1^T + b1)
    skinny_part<<<dim3(48, 4), 256, 0, stream>>>(xbuf, 768, W1 + (size_t)l * FF_DIM * 768, 192, part, FF_DIM);
    reduce_bias<<<64, 256, 0, stream>>>(part, 4, FF_DIM, fb1 + l * FF_DIM, 1, h1);
    // tq' = LN2(h1 @ W2^T + b2 + x), fused with next layer's q projection
    skinny_part<<<dim3(12, 16), 256, 0, stream>>>(h1, FF_DIM, W2 + (size_t)l * 768 * FF_DIM, 192, part, 768);
    if (l < LAYERS - 1) {
      reduce_ln_q<<<64, 256, 0, stream>>>(part, 16, fb2 + l * 768, xbuf,
                                          ln2_g + l * 768, ln2_b + l * 768, tq,
                                          Mbuf + (l + 1) * 4096, ln1_g + (l + 1) * 768,
                                          ln1_b + (l + 1) * 768, qMg, qMb);
    } else {
      reduce_ln_q<<<64, 256, 0, stream>>>(part, 16, fb2 + l * 768, xbuf,
                                          ln2_g + l * 768, ln2_b + l * 768, tq,
                                          nullptr, nullptr, nullptr, nullptr, nullptr);
    }
  }

  // ---- head ----
  mean_rows<<<192, 256, 0, stream>>>(tq, xm);
  skinny_part<<<dim3(16, 4), 256, 0, stream>>>(xm, 768, mlp_W, 192, part, 1024);
  reduce_bias<<<64, 256, 0, stream>>>(part, 4, 1024, mlp_b, 0, logits);
  top5_onehot<<<32, 256, 0, stream>>>(logits, out);
}

// Round 6
// 1929.061 us; speedup vs baseline: 4.0141x; 1.0824x over previous
//
#include <hip/hip_runtime.h>
#include <math.h>

#define E_DIM 768
#define NTOK 1025
#define B_DIM 32
#define NHEADS 12
#define HDIM 64
#define LAYERS 12
#define FF_DIM 3072
#define P2 576

// ---------------- helpers ----------------
__device__ __forceinline__ float block_reduce_sum(float v, float* red) {
  int tid = threadIdx.x;
  red[tid] = v;
  __syncthreads();
#pragma unroll
  for (int s = 128; s > 0; s >>= 1) {
    if (tid < s) red[tid] += red[tid + s];
    __syncthreads();
  }
  float r = red[0];
  __syncthreads();
  return r;
}

// ---------------- embed GEMM: 128x128 tile, 8x8 acc/thread ----------------
__global__ __launch_bounds__(256) void embed_gemm(
    const float* __restrict__ A, const float* __restrict__ W,
    const float* __restrict__ bias, const float* __restrict__ pos,
    float* __restrict__ scene) {
  __shared__ float Xs[16][132];
  __shared__ float Ws[16][132];
  int tid = threadIdx.x;
  int n0 = blockIdx.x * 128;
  int m0 = blockIdx.y * 128;
  int lr = tid >> 2;
  int lk = (tid & 3) << 2;
  int ty = tid >> 4, tx = tid & 15;
  float acc[8][8] = {};
  for (int k0 = 0; k0 < P2; k0 += 16) {
    float4 x0 = *(const float4*)(A + (size_t)(m0 + lr) * P2 + k0 + lk);
    float4 x1 = *(const float4*)(A + (size_t)(m0 + 64 + lr) * P2 + k0 + lk);
    float4 w0 = *(const float4*)(W + (size_t)(n0 + lr) * P2 + k0 + lk);
    float4 w1 = *(const float4*)(W + (size_t)(n0 + 64 + lr) * P2 + k0 + lk);
    __syncthreads();
    Xs[lk + 0][lr] = x0.x; Xs[lk + 1][lr] = x0.y; Xs[lk + 2][lr] = x0.z; Xs[lk + 3][lr] = x0.w;
    Xs[lk + 0][64 + lr] = x1.x; Xs[lk + 1][64 + lr] = x1.y; Xs[lk + 2][64 + lr] = x1.z; Xs[lk + 3][64 + lr] = x1.w;
    Ws[lk + 0][lr] = w0.x; Ws[lk + 1][lr] = w0.y; Ws[lk + 2][lr] = w0.z; Ws[lk + 3][lr] = w0.w;
    Ws[lk + 0][64 + lr] = w1.x; Ws[lk + 1][64 + lr] = w1.y; Ws[lk + 2][64 + lr] = w1.z; Ws[lk + 3][64 + lr] = w1.w;
    __syncthreads();
#pragma unroll
    for (int kk = 0; kk < 16; ++kk) {
      float4 a0 = *(const float4*)&Xs[kk][ty << 2];
      float4 a1 = *(const float4*)&Xs[kk][64 + (ty << 2)];
      float4 b0 = *(const float4*)&Ws[kk][tx << 2];
      float4 b1 = *(const float4*)&Ws[kk][64 + (tx << 2)];
      float av[8] = {a0.x, a0.y, a0.z, a0.w, a1.x, a1.y, a1.z, a1.w};
      float bv[8] = {b0.x, b0.y, b0.z, b0.w, b1.x, b1.y, b1.z, b1.w};
#pragma unroll
      for (int i = 0; i < 8; ++i)
#pragma unroll
        for (int j = 0; j < 8; ++j) acc[i][j] += av[i] * bv[j];
    }
  }
#pragma unroll
  for (int i = 0; i < 8; ++i) {
    int mloc = (i < 4) ? ((ty << 2) + i) : (64 + (ty << 2) + i - 4);
    int m = m0 + mloc;
    int b = m >> 10, nt = m & 1023;
    size_t row = ((size_t)b * NTOK + 1 + nt) * E_DIM;
    size_t prow = (size_t)(1 + nt) * E_DIM;
#pragma unroll
    for (int half = 0; half < 2; ++half) {
      int n = n0 + half * 64 + (tx << 2);
      float4 o4;
      o4.x = acc[i][half * 4 + 0] + bias[n + 0] + pos[prow + n + 0];
      o4.y = acc[i][half * 4 + 1] + bias[n + 1] + pos[prow + n + 1];
      o4.z = acc[i][half * 4 + 2] + bias[n + 2] + pos[prow + n + 2];
      o4.w = acc[i][half * 4 + 3] + bias[n + 3] + pos[prow + n + 3];
      *(float4*)&scene[row + n] = o4;
    }
  }
}

__global__ void scene_cls(const float* __restrict__ cls, const float* __restrict__ pos,
                          float* __restrict__ scene) {
  int b = blockIdx.x;
  for (int e = threadIdx.x; e < E_DIM; e += 256)
    scene[(size_t)b * NTOK * E_DIM + e] = cls[e] + pos[e];
}

__global__ __launch_bounds__(256) void ln_rows(const float* __restrict__ in, float* __restrict__ out) {
  __shared__ float red[256];
  int r = blockIdx.x, tid = threadIdx.x;
  const float* x = in + (size_t)r * E_DIM;
  float a0 = x[tid], a1 = x[tid + 256], a2 = x[tid + 512];
  float mean = block_reduce_sum(a0 + a1 + a2, red) * (1.f / 768.f);
  float d0 = a0 - mean, d1 = a1 - mean, d2 = a2 - mean;
  float var = block_reduce_sum(d0 * d0 + d1 * d1 + d2 * d2, red) * (1.f / 768.f);
  float rinv = rsqrtf(var + 1e-5f);
  float* o = out + (size_t)r * E_DIM;
  o[tid] = d0 * rinv; o[tid + 256] = d1 * rinv; o[tid + 512] = d2 * rinv;
}

__global__ __launch_bounds__(256) void tgt_init(
    const float* __restrict__ tmask, const float* __restrict__ W,
    const float* __restrict__ bias, const float* __restrict__ cls,
    const float* __restrict__ tpos, float* __restrict__ tq) {
  int b = blockIdx.x, tid = threadIdx.x;
  for (int e = tid; e < E_DIM; e += 256)
    tq[(size_t)(b * 2) * E_DIM + e] = cls[e] + tpos[e];
  const float* tm = tmask + (size_t)b * P2;
  for (int e = tid; e < E_DIM; e += 256) {
    const float* wr = W + (size_t)e * P2;
    float s = 0.f;
    for (int k = 0; k < P2; k += 4) {
      float4 w4 = *(const float4*)&wr[k];
      float4 t4 = *(const float4*)&tm[k];
      s += w4.x * t4.x + w4.y * t4.y + w4.z * t4.z + w4.w * t4.w;
    }
    tq[(size_t)(b * 2 + 1) * E_DIM + e] = s + bias[e] + tpos[E_DIM + e];
  }
}

__global__ void prep_m(const float* __restrict__ Wq, const float* __restrict__ Wk,
                       float* __restrict__ Mb) {
  int l = blockIdx.y;
  int idx = blockIdx.x * 256 + threadIdx.x;
  int d = idx >> 6, dp = idx & 63;
  const float* wq = Wq + l * 4096;
  const float* wk = Wk + l * 4096;
  float s = 0.f;
#pragma unroll 8
  for (int e = 0; e < 64; ++e) s += wq[e * 64 + d] * wk[e * 64 + dp];
  Mb[l * 4096 + idx] = s;
}

__global__ void prep_wvo(const float* __restrict__ Wv, const float* __restrict__ Wo,
                         float* __restrict__ Wvo) {
  int l = blockIdx.y;
  int idx = blockIdx.x * 256 + threadIdx.x;
  int ep = idx / 768, hd = idx % 768;
  int h = hd >> 6, d = hd & 63;
  const float* wv = Wv + (size_t)l * 4096;
  const float* wo = Wo + (size_t)l * 768 * 768 + (size_t)ep * 768 + h * 64;
  float s = 0.f;
#pragma unroll 8
  for (int ev = 0; ev < 64; ++ev) s += wv[ev * 64 + d] * wo[ev];
  Wvo[(size_t)l * 589824 + idx] = s;
}

// standalone qln (layer 0 only)
__global__ __launch_bounds__(256) void qln_qm(
    const float* __restrict__ tq, const float* __restrict__ g1,
    const float* __restrict__ b1, const float* __restrict__ Mb, int l,
    float* __restrict__ qMg, float* __restrict__ qMb) {
  __shared__ float q[768];
  __shared__ float qm[768];
  __shared__ float red[256];
  int r = blockIdx.x, tid = threadIdx.x;
  const float* x = tq + (size_t)r * E_DIM;
  float a0 = x[tid], a1 = x[tid + 256], a2 = x[tid + 512];
  float mean = block_reduce_sum(a0 + a1 + a2, red) * (1.f / 768.f);
  float d0 = a0 - mean, d1 = a1 - mean, d2 = a2 - mean;
  float var = block_reduce_sum(d0 * d0 + d1 * d1 + d2 * d2, red) * (1.f / 768.f);
  float rinv = rsqrtf(var + 1e-5f);
  const float* gl = g1 + l * E_DIM;
  const float* bl = b1 + l * E_DIM;
  q[tid] = d0 * rinv * gl[tid] + bl[tid];
  q[tid + 256] = d1 * rinv * gl[tid + 256] + bl[tid + 256];
  q[tid + 512] = d2 * rinv * gl[tid + 512] + bl[tid + 512];
  __syncthreads();
  const float* M = Mb + l * 4096;
  const float inv_scale = rsqrtf(768.f);
  for (int o = tid; o < 768; o += 256) {
    int h = o >> 6, dp = o & 63;
    const float* qh = q + h * 64;
    float s = 0.f;
#pragma unroll 8
    for (int d = 0; d < 64; ++d) s += qh[d] * M[d * 64 + dp];
    qm[o] = s;
    qMg[(size_t)r * E_DIM + o] = s * gl[o] * inv_scale;
  }
  __syncthreads();
  if (tid < NHEADS) {
    float acc = 0.f;
#pragma unroll 8
    for (int dp = 0; dp < 64; ++dp) acc += qm[tid * 64 + dp] * bl[tid * 64 + dp];
    qMb[r * NHEADS + tid] = acc * inv_scale;
  }
}

// ---------------- flash attention (f32 scene), register-cached chunks ----------------
#define ACH 272
__global__ __launch_bounds__(256) void attn_flash(
    const float* __restrict__ ns, const float* __restrict__ qMg,
    const float* __restrict__ qMb, const float* __restrict__ g1,
    const float* __restrict__ b1, int l, float* __restrict__ ctx) {
  __shared__ float red[256];
  __shared__ float sred[2][16];
  __shared__ float cred[2][16][64];
  int b = blockIdx.x / NHEADS;
  int h = blockIdx.x % NHEADS;
  int tid = threadIdx.x;
  int g = tid >> 4;
  int lane = tid & 15;
  int r0 = b * 2, r1 = r0 + 1;
  const float* nsb = ns + (size_t)b * NTOK * E_DIM + h * 64;
  float4 q0v = *(const float4*)(qMg + (size_t)r0 * E_DIM + h * 64 + lane * 4);
  float4 q1v = *(const float4*)(qMg + (size_t)r1 * E_DIM + h * 64 + lane * 4);
  float qb0 = qMb[r0 * NHEADS + h], qb1 = qMb[r1 * NHEADS + h];
  float m = -1e30f, s0 = 0.f, s1 = 0.f;
  float4 c0 = {0, 0, 0, 0}, c1 = {0, 0, 0, 0};
  float4 v[17];
  float e0a[17], e1a[17];
  for (int cb = 0; cb < NTOK; cb += ACH) {
    int ntk = NTOK - cb; if (ntk > ACH) ntk = ACH;
    int cnt = (ntk - g + 15) >> 4;
    float mloc = -1e30f;
#pragma unroll
    for (int i = 0; i < 17; ++i) {
      if (i < cnt) {
        int k = cb + g + (i << 4);
        float4 vv = *(const float4*)(nsb + (size_t)k * E_DIM + lane * 4);
        v[i] = vv;
        float p0 = vv.x * q0v.x + vv.y * q0v.y + vv.z * q0v.z + vv.w * q0v.w;
        float p1 = vv.x * q1v.x + vv.y * q1v.y + vv.z * q1v.z + vv.w * q1v.w;
#pragma unroll
        for (int off = 8; off; off >>= 1) {
          p0 += __shfl_xor(p0, off, 16);
          p1 += __shfl_xor(p1, off, 16);
        }
        float e0 = p0 + qb0, e1 = p1 + qb1;
        e0a[i] = e0; e1a[i] = e1;
        mloc = fmaxf(mloc, fmaxf(e0, e1));
      }
    }
    red[tid] = mloc;
    __syncthreads();
#pragma unroll
    for (int s = 128; s > 0; s >>= 1) {
      if (tid < s) red[tid] = fmaxf(red[tid], red[tid + s]);
      __syncthreads();
    }
    float mnew = fmaxf(m, red[0]);
    __syncthreads();
    if (mnew > m) {
      float f = expf(m - mnew);
      s0 *= f; s1 *= f;
      c0.x *= f; c0.y *= f; c0.z *= f; c0.w *= f;
      c1.x *= f; c1.y *= f; c1.z *= f; c1.w *= f;
      m = mnew;
    }
#pragma unroll
    for (int i = 0; i < 17; ++i) {
      if (i < cnt) {
        float p0 = expf(e0a[i] - m);
        float p1 = expf(e1a[i] - m);
        s0 += p0; s1 += p1;
        c0.x += p0 * v[i].x; c0.y += p0 * v[i].y; c0.z += p0 * v[i].z; c0.w += p0 * v[i].w;
        c1.x += p1 * v[i].x; c1.y += p1 * v[i].y; c1.z += p1 * v[i].z; c1.w += p1 * v[i].w;
      }
    }
  }
  if (lane == 0) { sred[0][g] = s0; sred[1][g] = s1; }
  *(float4*)&cred[0][g][lane * 4] = c0;
  *(float4*)&cred[1][g][lane * 4] = c1;
  __syncthreads();
  if (tid < 128) {
    int t = tid >> 6, dd = tid & 63;
    int o = h * 64 + dd;
    float stot = 0.f, cs = 0.f;
#pragma unroll
    for (int gg = 0; gg < 16; ++gg) { stot += sred[t][gg]; cs += cred[t][gg][dd]; }
    float inv = 1.f / stot;
    ctx[(size_t)(r0 + t) * E_DIM + o] = cs * inv * g1[l * E_DIM + o] + b1[l * E_DIM + o];
  }
}

// ---------------- skinny GEMM (M=64) partial over k-chunk ----------------
__global__ __launch_bounds__(256) void skinny_part(
    const float* __restrict__ X, int K, const float* __restrict__ W,
    int kchunk, float* __restrict__ part, int N) {
  __shared__ float Xs[16][64];
  __shared__ float Ws[16][64];
  int tid = threadIdx.x;
  int n0 = blockIdx.x * 64;
  int s = blockIdx.y;
  int kbeg = s * kchunk;
  int lr = tid >> 2;
  int lk = (tid & 3) << 2;
  int ty = tid >> 4, tx = tid & 15;
  float acc[4][4] = {};
  for (int k0 = kbeg; k0 < kbeg + kchunk; k0 += 16) {
    float4 xv = *(const float4*)(X + (size_t)lr * K + k0 + lk);
    float4 wv = *(const float4*)(W + (size_t)(n0 + lr) * K + k0 + lk);
    __syncthreads();
    Xs[lk + 0][lr] = xv.x; Xs[lk + 1][lr] = xv.y; Xs[lk + 2][lr] = xv.z; Xs[lk + 3][lr] = xv.w;
    Ws[lk + 0][lr] = wv.x; Ws[lk + 1][lr] = wv.y; Ws[lk + 2][lr] = wv.z; Ws[lk + 3][lr] = wv.w;
    __syncthreads();
#pragma unroll
    for (int kk = 0; kk < 16; ++kk) {
      float4 a4 = *(const float4*)&Xs[kk][ty << 2];
      float4 b4 = *(const float4*)&Ws[kk][tx << 2];
      float av[4] = {a4.x, a4.y, a4.z, a4.w};
      float bv[4] = {b4.x, b4.y, b4.z, b4.w};
#pragma unroll
      for (int i = 0; i < 4; ++i)
#pragma unroll
        for (int j = 0; j < 4; ++j) acc[i][j] += av[i] * bv[j];
    }
  }
#pragma unroll
  for (int i = 0; i < 4; ++i) {
    int mm = (ty << 2) + i;
    float4 o4 = make_float4(acc[i][0], acc[i][1], acc[i][2], acc[i][3]);
    *(float4*)&part[((size_t)s * 64 + mm) * N + n0 + (tx << 2)] = o4;
  }
}

// FF2 skinny: X = relu(sum_{s<4} part1[s] + b1) computed inline (K=3072), out N=768
__global__ __launch_bounds__(256) void skinny_h1_part(
    const float* __restrict__ part1, const float* __restrict__ b1,
    const float* __restrict__ W, int kchunk, float* __restrict__ part2) {
  __shared__ float Xs[16][64];
  __shared__ float Ws[16][64];
  const int K = 3072, N = 768;
  int tid = threadIdx.x;
  int n0 = blockIdx.x * 64;
  int s = blockIdx.y;
  int kbeg = s * kchunk;
  int lr = tid >> 2;
  int lk = (tid & 3) << 2;
  int ty = tid >> 4, tx = tid & 15;
  float acc[4][4] = {};
  for (int k0 = kbeg; k0 < kbeg + kchunk; k0 += 16) {
    float4 x0 = *(const float4*)(part1 + (size_t)lr * K + k0 + lk);
    float4 x1 = *(const float4*)(part1 + (size_t)(64 + lr) * K + k0 + lk);
    float4 x2 = *(const float4*)(part1 + (size_t)(128 + lr) * K + k0 + lk);
    float4 x3 = *(const float4*)(part1 + (size_t)(192 + lr) * K + k0 + lk);
    float4 bb = *(const float4*)(b1 + k0 + lk);
    float4 xv;
    xv.x = fmaxf(x0.x + x1.x + x2.x + x3.x + bb.x, 0.f);
    xv.y = fmaxf(x0.y + x1.y + x2.y + x3.y + bb.y, 0.f);
    xv.z = fmaxf(x0.z + x1.z + x2.z + x3.z + bb.z, 0.f);
    xv.w = fmaxf(x0.w + x1.w + x2.w + x3.w + bb.w, 0.f);
    float4 wv = *(const float4*)(W + (size_t)(n0 + lr) * K + k0 + lk);
    __syncthreads();
    Xs[lk + 0][lr] = xv.x; Xs[lk + 1][lr] = xv.y; Xs[lk + 2][lr] = xv.z; Xs[lk + 3][lr] = xv.w;
    Ws[lk + 0][lr] = wv.x; Ws[lk + 1][lr] = wv.y; Ws[lk + 2][lr] = wv.z; Ws[lk + 3][lr] = wv.w;
    __syncthreads();
#pragma unroll
    for (int kk = 0; kk < 16; ++kk) {
      float4 a4 = *(const float4*)&Xs[kk][ty << 2];
      float4 b4 = *(const float4*)&Ws[kk][tx << 2];
      float av[4] = {a4.x, a4.y, a4.z, a4.w};
      float bv[4] = {b4.x, b4.y, b4.z, b4.w};
#pragma unroll
      for (int i = 0; i < 4; ++i)
#pragma unroll
        for (int j = 0; j < 4; ++j) acc[i][j] += av[i] * bv[j];
    }
  }
#pragma unroll
  for (int i = 0; i < 4; ++i) {
    int mm = (ty << 2) + i;
    float4 o4 = make_float4(acc[i][0], acc[i][1], acc[i][2], acc[i][3]);
    *(float4*)&part2[((size_t)s * 64 + mm) * N + n0 + (tx << 2)] = o4;
  }
}

// reduce partials + bias + residual + LN; optional fused next-layer qproj; optional xm accum
__global__ __launch_bounds__(256) void reduce_ln_q(
    const float* __restrict__ part, int S, const float* __restrict__ bias,
    const float* __restrict__ res, const float* __restrict__ g,
    const float* __restrict__ bsh, float* __restrict__ out,
    const float* __restrict__ Mb_next, const float* __restrict__ g1n,
    const float* __restrict__ b1n, float* __restrict__ qMg,
    float* __restrict__ qMb, float* __restrict__ xmean) {
  __shared__ float red[256];
  __shared__ float q[768];
  __shared__ float qm[768];
  int m = blockIdx.x, tid = threadIdx.x;
  float t[3];
#pragma unroll
  for (int c = 0; c < 3; ++c) {
    int n = tid + c * 256;
    float s = 0.f;
    for (int i = 0; i < S; ++i) s += part[((size_t)i * 64 + m) * 768 + n];
    t[c] = s + bias[n] + res[(size_t)m * 768 + n];
  }
  float mean = block_reduce_sum(t[0] + t[1] + t[2], red) * (1.f / 768.f);
  float d0 = t[0] - mean, d1 = t[1] - mean, d2 = t[2] - mean;
  float var = block_reduce_sum(d0 * d0 + d1 * d1 + d2 * d2, red) * (1.f / 768.f);
  float rinv = rsqrtf(var + 1e-5f);
  float y0 = d0 * rinv * g[tid] + bsh[tid];
  float y1 = d1 * rinv * g[tid + 256] + bsh[tid + 256];
  float y2 = d2 * rinv * g[tid + 512] + bsh[tid + 512];
  out[(size_t)m * 768 + tid] = y0;
  out[(size_t)m * 768 + tid + 256] = y1;
  out[(size_t)m * 768 + tid + 512] = y2;
  if (xmean) {
    float* xr = xmean + (size_t)(m >> 1) * 768;
    atomicAdd(&xr[tid], 0.5f * y0);
    atomicAdd(&xr[tid + 256], 0.5f * y1);
    atomicAdd(&xr[tid + 512], 0.5f * y2);
  }
  if (Mb_next) {
    float mean2 = block_reduce_sum(y0 + y1 + y2, red) * (1.f / 768.f);
    float e0 = y0 - mean2, e1 = y1 - mean2, e2 = y2 - mean2;
    float var2 = block_reduce_sum(e0 * e0 + e1 * e1 + e2 * e2, red) * (1.f / 768.f);
    float rinv2 = rsqrtf(var2 + 1e-5f);
    q[tid] = e0 * rinv2 * g1n[tid] + b1n[tid];
    q[tid + 256] = e1 * rinv2 * g1n[tid + 256] + b1n[tid + 256];
    q[tid + 512] = e2 * rinv2 * g1n[tid + 512] + b1n[tid + 512];
    __syncthreads();
    const float inv_scale = rsqrtf(768.f);
    for (int o = tid; o < 768; o += 256) {
      int h = o >> 6, dp = o & 63;
      const float* qh = q + h * 64;
      float s = 0.f;
#pragma unroll 8
      for (int d = 0; d < 64; ++d) s += qh[d] * Mb_next[d * 64 + dp];
      qm[o] = s;
      qMg[(size_t)m * E_DIM + o] = s * g1n[o] * inv_scale;
    }
    __syncthreads();
    if (tid < NHEADS) {
      float acc = 0.f;
#pragma unroll 8
      for (int dp = 0; dp < 64; ++dp) acc += qm[tid * 64 + dp] * b1n[tid * 64 + dp];
      qMb[m * NHEADS + tid] = acc * inv_scale;
    }
  }
}

// head: logits row from 4 partials + bias, then top-5 one-hot
__global__ __launch_bounds__(256) void top5_from_parts(
    const float* __restrict__ part, const float* __restrict__ bias,
    float* __restrict__ out) {
  __shared__ float v[1024];
  __shared__ float bv[256];
  __shared__ int bi[256];
  int b = blockIdx.x, tid = threadIdx.x;
  for (int i = tid; i < 1024; i += 256) {
    float s = part[(size_t)(0 * 64 + b) * 1024 + i] + part[(size_t)(1 * 64 + b) * 1024 + i] +
              part[(size_t)(2 * 64 + b) * 1024 + i] + part[(size_t)(3 * 64 + b) * 1024 + i];
    v[i] = s + bias[i];
  }
  float* ob = out + (size_t)b * 5 * NTOK;
  for (int i = tid; i < 5 * NTOK; i += 256) ob[i] = 0.f;
  __syncthreads();
  for (int it = 0; it < 5; ++it) {
    float best = -1e38f;
    int bidx = 0x7fffffff;
    for (int i = tid; i < 1024; i += 256) {
      float x = v[i];
      if (x > best || (x == best && i < bidx)) { best = x; bidx = i; }
    }
    bv[tid] = best; bi[tid] = bidx;
    __syncthreads();
    for (int s = 128; s > 0; s >>= 1) {
      if (tid < s) {
        if (bv[tid + s] > bv[tid] || (bv[tid + s] == bv[tid] && bi[tid + s] < bi[tid])) {
          bv[tid] = bv[tid + s]; bi[tid] = bi[tid + s];
        }
      }
      __syncthreads();
    }
    if (tid == 0) {
      ob[it * NTOK + bi[0]] = 1.0f;
      v[bi[0]] = -1e38f;
    }
    __syncthreads();
  }
}

extern "C" void kernel_launch(void* const* d_in, const int* in_sizes, int n_in,
                              void* d_out, int out_size, void* d_ws, size_t ws_size,
                              hipStream_t stream) {
  const float* scene_masks = (const float*)d_in[0];
  const float* target_mask = (const float*)d_in[1];
  const float* emb_W = (const float*)d_in[2];
  const float* emb_b = (const float*)d_in[3];
  const float* class_embed = (const float*)d_in[4];
  const float* scene_pos = (const float*)d_in[5];
  const float* target_pos = (const float*)d_in[6];
  const float* ln1_g = (const float*)d_in[7];
  const float* ln1_b = (const float*)d_in[8];
  const float* ln2_g = (const float*)d_in[9];
  const float* ln2_b = (const float*)d_in[10];
  const float* Wq = (const float*)d_in[11];
  const float* Wk = (const float*)d_in[12];
  const float* Wv = (const float*)d_in[13];
  const float* Wo = (const float*)d_in[14];
  const float* bo = (const float*)d_in[15];
  const float* W1 = (const float*)d_in[16];
  const float* fb1 = (const float*)d_in[17];
  const float* W2 = (const float*)d_in[18];
  const float* fb2 = (const float*)d_in[19];
  const float* mlp_W = (const float*)d_in[20];
  const float* mlp_b = (const float*)d_in[21];
  float* out = (float*)d_out;

  float* ws = (float*)d_ws;
  float* scene = ws;                       // 25190400
  float* Mbuf = scene + 25190400;          // 49152
  float* Wvo = Mbuf + 49152;               // 7077888
  float* tq = Wvo + 7077888;               // 49152
  float* qMg = tq + 49152;                 // 49152
  float* qMb = qMg + 49152;                // 768
  float* ctxf = qMb + 768;                 // 49152
  float* xbuf = ctxf + 49152;              // 49152
  float* xm = xbuf + 49152;                // 49152 (64x768, rows>=32 zero)
  float* partA = xm + 49152;               // 786432 (up to 16x64x768 / 4x64x1024)
  float* partB = partA + 786432;           // 786432 (4x64x3072)

  // ---- setup ----
  embed_gemm<<<dim3(6, 256), 256, 0, stream>>>(scene_masks, emb_W, emb_b, scene_pos, scene);
  scene_cls<<<32, 256, 0, stream>>>(class_embed, scene_pos, scene);
  ln_rows<<<32 * NTOK, 256, 0, stream>>>(scene, scene);
  tgt_init<<<32, 256, 0, stream>>>(target_mask, emb_W, emb_b, class_embed, target_pos, tq);
  prep_m<<<dim3(16, 12), 256, 0, stream>>>(Wq, Wk, Mbuf);
  prep_wvo<<<dim3(2304, 12), 256, 0, stream>>>(Wv, Wo, Wvo);
  hipMemsetAsync(xm, 0, 49152 * sizeof(float), stream);
  qln_qm<<<64, 256, 0, stream>>>(tq, ln1_g, ln1_b, Mbuf, 0, qMg, qMb);

  // ---- 12 transformer blocks ----
  for (int l = 0; l < LAYERS; ++l) {
    attn_flash<<<32 * NHEADS, 256, 0, stream>>>(scene, qMg, qMb, ln1_g, ln1_b, l, ctxf);
    // out2 = ctx @ Wvo_l^T + bo; x = LN1(out2 + tq)
    skinny_part<<<dim3(12, 8), 256, 0, stream>>>(ctxf, 768, Wvo + (size_t)l * 589824, 96, partA, 768);
    reduce_ln_q<<<64, 256, 0, stream>>>(partA, 8, bo + l * 768, tq,
                                        ln1_g + l * 768, ln1_b + l * 768, xbuf,
                                        nullptr, nullptr, nullptr, nullptr, nullptr, nullptr);
    // FF1 partials (no bias/relu — folded into FF2)
    skinny_part<<<dim3(48, 4), 256, 0, stream>>>(xbuf, 768, W1 + (size_t)l * FF_DIM * 768, 192, partB, FF_DIM);
    // FF2 with inline h1 = relu(sum parts + b1)
    skinny_h1_part<<<dim3(12, 16), 256, 0, stream>>>(partB, fb1 + l * FF_DIM,
                                                     W2 + (size_t)l * 768 * FF_DIM, 192, partA);
    // tq' = LN2(ff2 + b2 + x), fused next-layer qproj; layer 11 also accumulates xm
    if (l < LAYERS - 1)
      reduce_ln_q<<<64, 256, 0, stream>>>(partA, 16, fb2 + l * 768, xbuf,
                                          ln2_g + l * 768, ln2_b + l * 768, tq,
                                          Mbuf + (l + 1) * 4096, ln1_g + (l + 1) * 768,
                                          ln1_b + (l + 1) * 768, qMg, qMb, nullptr);
    else
      reduce_ln_q<<<64, 256, 0, stream>>>(partA, 16, fb2 + l * 768, xbuf,
                                          ln2_g + l * 768, ln2_b + l * 768, tq,
                                          nullptr, nullptr, nullptr, nullptr, nullptr, xm);
  }

  // ---- head ----
  skinny_part<<<dim3(16, 4), 256, 0, stream>>>(xm, 768, mlp_W, 192, partA, 1024);
  top5_from_parts<<<32, 256, 0, stream>>>(partA, mlp_b, out);
}